// Round 1
// baseline (395.766 us; speedup 1.0000x reference)
//
#include <hip/hip_runtime.h>
#include <cstdint>
#include <cstddef>
#include <math.h>

#define SEQ  2048
#define DIN  1024
#define DH   64
#define NB   4

// ======================= host-side numpy RNG replication =======================
// Replicates: rng = np.random.default_rng(0); rng.choice(2048,3,replace=False) x2
// Chain: SeedSequence(0) -> PCG64 (XSL-RR 128/64) -> Lemire bounded32 ->
//        Floyd's algorithm (hash set of 4) -> partial Fisher-Yates shuffle.
namespace nprng {

struct PCG64 {
  __uint128_t state, inc;
  bool has_uint32;
  uint32_t uinteger;
};

static inline void pcg_step(PCG64 &g) {
  const __uint128_t MULT =
      (((__uint128_t)0x2360ed051fc65da4ULL) << 64) | 0x4385df649fccf645ULL;
  g.state = g.state * MULT + g.inc;
}

static inline uint64_t pcg_output(const PCG64 &g) {
  uint64_t hi = (uint64_t)(g.state >> 64);
  uint64_t lo = (uint64_t)g.state;
  uint64_t x = hi ^ lo;
  unsigned rot = (unsigned)(g.state >> 122) & 63u;
  return (x >> rot) | (x << ((64u - rot) & 63u));
}

static inline uint64_t pcg_next64(PCG64 &g) { pcg_step(g); return pcg_output(g); }

static inline uint32_t pcg_next32(PCG64 &g) {
  if (g.has_uint32) { g.has_uint32 = false; return g.uinteger; }
  uint64_t n = pcg_next64(g);
  g.has_uint32 = true;
  g.uinteger = (uint32_t)(n >> 32);
  return (uint32_t)(n & 0xffffffffu);
}

static inline void pcg_seed_from_seedseq0(PCG64 &g) {
  // SeedSequence(entropy=0, pool_size=4)
  const uint32_t MULT_A = 0x931e8875u;
  const uint32_t MULT_B = 0x58f38dedu;
  const uint32_t MIX_L  = 0xca01f9ddu;
  const uint32_t MIX_R  = 0x4973f715u;
  uint32_t hc = 0x43b0d7e5u;  // INIT_A
  uint32_t pool[4];
  // hashmix(v): v ^= hc; hc *= MULT_A; v *= hc; v ^= v>>16
  for (int i = 0; i < 4; i++) {
    uint32_t v = 0u;          // assembled entropy = [0]
    v ^= hc; hc *= MULT_A; v *= hc; v ^= v >> 16;
    pool[i] = v;
  }
  for (int is = 0; is < 4; is++) {
    for (int id = 0; id < 4; id++) {
      if (is == id) continue;
      uint32_t h = pool[is];
      h ^= hc; hc *= MULT_A; h *= hc; h ^= h >> 16;
      uint32_t r = (pool[id] * MIX_L) ^ (h * MIX_R);
      r ^= r >> 16;
      pool[id] = r;
    }
  }
  // generate_state(4, uint64) -> 8x uint32, little-endian pairs
  uint32_t hb = 0x8b51f9ddu;  // INIT_B
  uint32_t w[8];
  for (int i = 0; i < 8; i++) {
    uint32_t v = pool[i & 3];
    v ^= hb; hb *= MULT_B; v *= hb; v ^= v >> 16;
    w[i] = v;
  }
  uint64_t sv[4];
  for (int k = 0; k < 4; k++)
    sv[k] = (uint64_t)w[2 * k] | ((uint64_t)w[2 * k + 1] << 32);
  // pcg64_set_seed: initstate = (sv0<<64)|sv1 ; initseq = (sv2<<64)|sv3
  __uint128_t initstate = (((__uint128_t)sv[0]) << 64) | sv[1];
  __uint128_t initseq   = (((__uint128_t)sv[2]) << 64) | sv[3];
  g.state = 0; g.inc = (initseq << 1) | 1;
  pcg_step(g);
  g.state += initstate;
  pcg_step(g);
  g.has_uint32 = false; g.uinteger = 0;
}

// random_bounded_uint64(off=0, rng<=0xFFFFFFFE, use_masked=0) 32-bit Lemire path
static inline uint32_t bounded32(PCG64 &g, uint32_t rng /*inclusive max*/) {
  if (rng == 0) return 0;
  const uint32_t rng_excl = rng + 1u;
  uint64_t m = (uint64_t)pcg_next32(g) * (uint64_t)rng_excl;
  uint32_t leftover = (uint32_t)m;
  if (leftover < rng_excl) {
    const uint32_t threshold = (uint32_t)(0xffffffffu - rng) % rng_excl;
    while (leftover < threshold) {
      m = (uint64_t)pcg_next32(g) * (uint64_t)rng_excl;
      leftover = (uint32_t)m;
    }
  }
  return (uint32_t)(m >> 32);
}

// Generator.choice(2048, 3, replace=False, shuffle=True): Floyd + shuffle
static inline void choice3_2048(PCG64 &g, long long idx[3]) {
  const int pop = 2048, sz = 3;
  uint64_t hs[4] = { (uint64_t)-1, (uint64_t)-1, (uint64_t)-1, (uint64_t)-1 };
  const uint64_t mask = 3;  // set_size = (uint64)(1.2*3)=3 -> gen_mask=3 -> size 4
  for (int j = pop - sz; j < pop; j++) {
    uint64_t val = (uint64_t)bounded32(g, (uint32_t)j);
    uint64_t loc = val & mask;
    while (hs[loc] != (uint64_t)-1 && hs[loc] != val) loc = (loc + 1) & mask;
    if (hs[loc] == (uint64_t)-1) {
      hs[loc] = val;
      idx[j - pop + sz] = (long long)val;
    } else {
      loc = (uint64_t)j & mask;
      while (hs[loc] != (uint64_t)-1) loc = (loc + 1) & mask;
      hs[loc] = (uint64_t)j;
      idx[j - pop + sz] = (long long)j;
    }
  }
  // _shuffle_int(3, 1, idx): i = 2, 1
  for (int i = 2; i >= 1; i--) {
    uint32_t j = bounded32(g, (uint32_t)i);
    long long t = idx[j]; idx[j] = idx[i]; idx[i] = t;
  }
}

}  // namespace nprng

// =============================== projections ==================================
// C[M=8192, 64] = X[M,1024] @ W[1024,64] + bias.  blockIdx.y selects q/k/v.
// 64x64 output tile per block, 256 threads, 4x4 register micro-tiles.
__global__ __launch_bounds__(256) void proj_kernel(
    const float* __restrict__ xq, const float* __restrict__ xk,
    const float* __restrict__ xv,
    const float* __restrict__ Wq, const float* __restrict__ bq,
    const float* __restrict__ Wk, const float* __restrict__ bk,
    const float* __restrict__ Wv, const float* __restrict__ bv,
    float* __restrict__ QP, float* __restrict__ KP, float* __restrict__ VP) {
  const int proj = blockIdx.y;
  const float* X    = (proj == 0) ? xq : (proj == 1) ? xk : xv;
  const float* W    = (proj == 0) ? Wq : (proj == 1) ? Wk : Wv;
  const float* bias = (proj == 0) ? bq : (proj == 1) ? bk : bv;
  float* outp       = (proj == 0) ? QP : (proj == 1) ? KP : VP;

  const int m0  = blockIdx.x * 64;
  const int tid = threadIdx.x;
  const int ty  = tid >> 4;   // 0..15 -> rows 4ty..4ty+3
  const int tx  = tid & 15;   // 0..15 -> cols 4tx..4tx+3

  __shared__ float Xs[64][65];  // +1 pad breaks stride-64 bank aliasing
  __shared__ float Ws[64][65];

  float acc[4][4] = {};

  for (int k0 = 0; k0 < DIN; k0 += 64) {
    // stage 64x64 chunks of X and W (float4 coalesced)
#pragma unroll
    for (int it = 0; it < 4; it++) {
      int lin = it * 256 + tid;            // 0..1023
      int r = lin >> 4, c4 = (lin & 15) << 2;
      float4 v = *(const float4*)(X + (size_t)(m0 + r) * DIN + k0 + c4);
      Xs[r][c4] = v.x; Xs[r][c4 + 1] = v.y; Xs[r][c4 + 2] = v.z; Xs[r][c4 + 3] = v.w;
      float4 w = *(const float4*)(W + (size_t)(k0 + r) * DH + c4);
      Ws[r][c4] = w.x; Ws[r][c4 + 1] = w.y; Ws[r][c4 + 2] = w.z; Ws[r][c4 + 3] = w.w;
    }
    __syncthreads();

#pragma unroll 8
    for (int kk = 0; kk < 64; kk++) {
      float a[4], bb[4];
#pragma unroll
      for (int i = 0; i < 4; i++) a[i] = Xs[4 * ty + i][kk];
#pragma unroll
      for (int j = 0; j < 4; j++) bb[j] = Ws[kk][4 * tx + j];
#pragma unroll
      for (int i = 0; i < 4; i++)
#pragma unroll
        for (int j = 0; j < 4; j++) acc[i][j] += a[i] * bb[j];
    }
    __syncthreads();
  }

#pragma unroll
  for (int i = 0; i < 4; i++) {
    float4 o4;
    o4.x = acc[i][0] + bias[4 * tx + 0];
    o4.y = acc[i][1] + bias[4 * tx + 1];
    o4.z = acc[i][2] + bias[4 * tx + 2];
    o4.w = acc[i][3] + bias[4 * tx + 3];
    *(float4*)(outp + (size_t)(m0 + 4 * ty + i) * DH + (4 * tx)) = o4;
  }
}

// ============================ flash attention =================================
// One block = (batch b, 32 query rows). 128 threads: ty=tid>>4 (8 row-groups of
// 4 rows), tx=tid&15 (16 cols-groups of 4). Online softmax over 64-key tiles.
// Causal mask only needed on the LAST processed tile; 3 global pairs with
// C >= kend merged in an epilogue fixup.
__global__ __launch_bounds__(128) void attn_kernel(
    const float* __restrict__ QP, const float* __restrict__ KP,
    const float* __restrict__ VP, float* __restrict__ out,
    int R0, int C0, int R1, int C1, int R2, int C2) {
  const int b   = blockIdx.y;
  const int q0  = blockIdx.x * 32;
  const int tid = threadIdx.x;
  const int ty  = tid >> 4;   // 0..7
  const int tx  = tid & 15;   // 0..15

  __shared__ float Qs[32][65];
  __shared__ float Ks[64][65];
  __shared__ float Vs[64][65];
  __shared__ float Ps[32][65];

  const float* Qg = QP + ((size_t)b * SEQ + q0) * DH;
  const float* Kg = KP + (size_t)b * SEQ * DH;
  const float* Vg = VP + (size_t)b * SEQ * DH;

  // stage Q tile (32x64)
#pragma unroll
  for (int it = 0; it < 4; it++) {
    int lin = it * 128 + tid;            // 0..511
    int r = lin >> 4, c4 = (lin & 15) << 2;
    float4 v = *(const float4*)(Qg + (size_t)r * DH + c4);
    Qs[r][c4] = v.x; Qs[r][c4 + 1] = v.y; Qs[r][c4 + 2] = v.z; Qs[r][c4 + 3] = v.w;
  }

  float m_i[4], l_i[4], O[4][4];
#pragma unroll
  for (int i = 0; i < 4; i++) {
    m_i[i] = -INFINITY;
    l_i[i] = 0.f;
#pragma unroll
    for (int j = 0; j < 4; j++) O[i][j] = 0.f;
  }

  const int ntiles = (q0 + 95) >> 6;  // ceil((q0+32)/64)
  for (int t = 0; t < ntiles; t++) {
    const int k0 = t << 6;
    const bool maskt = (t == ntiles - 1);  // only last tile crosses diagonal

    // stage K,V tiles (64x64 each)
#pragma unroll
    for (int it = 0; it < 8; it++) {
      int lin = it * 128 + tid;          // 0..1023
      int r = lin >> 4, c4 = (lin & 15) << 2;
      float4 kv = *(const float4*)(Kg + (size_t)(k0 + r) * DH + c4);
      Ks[r][c4] = kv.x; Ks[r][c4 + 1] = kv.y; Ks[r][c4 + 2] = kv.z; Ks[r][c4 + 3] = kv.w;
      float4 vv = *(const float4*)(Vg + (size_t)(k0 + r) * DH + c4);
      Vs[r][c4] = vv.x; Vs[r][c4 + 1] = vv.y; Vs[r][c4 + 2] = vv.z; Vs[r][c4 + 3] = vv.w;
    }
    __syncthreads();

    // scores S = Q K^T (rows 4ty.., keys 4tx..)
    float s[4][4] = {};
#pragma unroll 8
    for (int kk = 0; kk < 64; kk++) {
      float a[4], bb[4];
#pragma unroll
      for (int i = 0; i < 4; i++) a[i] = Qs[4 * ty + i][kk];
#pragma unroll
      for (int j = 0; j < 4; j++) bb[j] = Ks[4 * tx + j][kk];
#pragma unroll
      for (int i = 0; i < 4; i++)
#pragma unroll
        for (int j = 0; j < 4; j++) s[i][j] += a[i] * bb[j];
    }

    // scale, mask (causal + global-pair allowance), row max
    float mt[4];
#pragma unroll
    for (int i = 0; i < 4; i++) {
      const int row = q0 + 4 * ty + i;
#pragma unroll
      for (int j = 0; j < 4; j++) {
        float lg = s[i][j] * 0.125f;     // (scores + mask)/sqrt(64)
        if (maskt) {
          const int col = k0 + 4 * tx + j;
          bool ok = (col <= row) || (row == R0 && col == C0) ||
                    (row == R1 && col == C1) || (row == R2 && col == C2);
          if (!ok) lg = -INFINITY;
        }
        s[i][j] = lg;
      }
      mt[i] = fmaxf(fmaxf(s[i][0], s[i][1]), fmaxf(s[i][2], s[i][3]));
    }
#pragma unroll
    for (int i = 0; i < 4; i++)
      for (int off = 8; off >= 1; off >>= 1)
        mt[i] = fmaxf(mt[i], __shfl_xor(mt[i], off, 64));

    // online softmax update
    float alpha[4], lsum[4];
#pragma unroll
    for (int i = 0; i < 4; i++) {
      const float mn = fmaxf(m_i[i], mt[i]);   // finite: every row has >=1 key
      alpha[i] = __expf(m_i[i] - mn);          // first tile: exp(-inf)=0
      m_i[i] = mn;
      float ps = 0.f;
#pragma unroll
      for (int j = 0; j < 4; j++) {
        const float p = __expf(s[i][j] - mn);  // masked -inf -> 0
        s[i][j] = p;
        ps += p;
      }
      lsum[i] = ps;
    }
#pragma unroll
    for (int i = 0; i < 4; i++) {
      for (int off = 8; off >= 1; off >>= 1)
        lsum[i] += __shfl_xor(lsum[i], off, 64);
      l_i[i] = l_i[i] * alpha[i] + lsum[i];
#pragma unroll
      for (int j = 0; j < 4; j++) {
        O[i][j] *= alpha[i];
        Ps[4 * ty + i][4 * tx + j] = s[i][j];
      }
    }
    __syncthreads();

    // O += P V  (rows 4ty.., dims 4tx..)
#pragma unroll 8
    for (int kk = 0; kk < 64; kk++) {
      float pa[4], vb[4];
#pragma unroll
      for (int i = 0; i < 4; i++) pa[i] = Ps[4 * ty + i][kk];
#pragma unroll
      for (int j = 0; j < 4; j++) vb[j] = Vs[kk][4 * tx + j];
#pragma unroll
      for (int i = 0; i < 4; i++)
#pragma unroll
        for (int j = 0; j < 4; j++) O[i][j] += pa[i] * vb[j];
    }
    __syncthreads();
  }

  // epilogue fixup: global pairs beyond the processed key range
  const int kend = ntiles << 6;
#pragma unroll
  for (int pidx = 0; pidx < 3; pidx++) {
    const int R = (pidx == 0) ? R0 : (pidx == 1) ? R1 : R2;
    const int C = (pidx == 0) ? C0 : (pidx == 1) ? C1 : C2;
    if (C >= kend && R >= q0 && R < q0 + 32) {
      const int lr = R - q0;
      if (ty == (lr >> 2)) {             // the 16 lanes owning this row
        const int io = lr & 3;
        const float* krow = Kg + (size_t)C * DH;
        const float* vrow = Vg + (size_t)C * DH;
        float part = 0.f;
#pragma unroll
        for (int d = 0; d < 4; d++) part += Qs[lr][4 * tx + d] * krow[4 * tx + d];
        for (int off = 8; off >= 1; off >>= 1) part += __shfl_xor(part, off, 64);
        const float lg = part * 0.125f;
        const float mn = fmaxf(m_i[io], lg);
        const float al = __expf(m_i[io] - mn);
        const float p  = __expf(lg - mn);
        m_i[io] = mn;
        l_i[io] = l_i[io] * al + p;
#pragma unroll
        for (int j = 0; j < 4; j++)
          O[io][j] = O[io][j] * al + p * vrow[4 * tx + j];
      }
    }
  }

  // normalize + store
#pragma unroll
  for (int i = 0; i < 4; i++) {
    const float inv = 1.0f / l_i[i];
    float4 o4;
    o4.x = O[i][0] * inv; o4.y = O[i][1] * inv;
    o4.z = O[i][2] * inv; o4.w = O[i][3] * inv;
    *(float4*)(out + ((size_t)b * SEQ + q0 + 4 * ty + i) * DH + (4 * tx)) = o4;
  }
}

// ================================= launch =====================================
extern "C" void kernel_launch(void* const* d_in, const int* in_sizes, int n_in,
                              void* d_out, int out_size, void* d_ws,
                              size_t ws_size, hipStream_t stream) {
  const float* xq = (const float*)d_in[0];
  const float* xk = (const float*)d_in[1];
  const float* xv = (const float*)d_in[2];
  const float* Wq = (const float*)d_in[3];
  const float* bq = (const float*)d_in[4];
  const float* Wk = (const float*)d_in[5];
  const float* bk = (const float*)d_in[6];
  const float* Wv = (const float*)d_in[7];
  const float* bv = (const float*)d_in[8];
  float* out = (float*)d_out;

  // workspace: Q,K,V projections, 2 MB each (needs 6 MB of d_ws)
  float* QP = (float*)d_ws;
  float* KP = QP + (size_t)NB * SEQ * DH;
  float* VP = KP + (size_t)NB * SEQ * DH;

  // replicate np.random.default_rng(0).choice(2048,3,replace=False) twice
  nprng::PCG64 g;
  nprng::pcg_seed_from_seedseq0(g);
  long long rows[3], cols[3];
  nprng::choice3_2048(g, rows);  // g_rows (query rows of global pairs)
  nprng::choice3_2048(g, cols);  // g_cols (key cols of global pairs)

  dim3 pgrid(NB * SEQ / 64, 3);
  proj_kernel<<<pgrid, 256, 0, stream>>>(xq, xk, xv, Wq, bq, Wk, bk, Wv, bv,
                                         QP, KP, VP);

  dim3 agrid(SEQ / 32, NB);
  attn_kernel<<<agrid, 128, 0, stream>>>(
      QP, KP, VP, out, (int)rows[0], (int)cols[0], (int)rows[1], (int)cols[1],
      (int)rows[2], (int)cols[2]);
}

// Round 2
// 190.613 us; speedup vs baseline: 2.0763x; 2.0763x over previous
//
#include <hip/hip_runtime.h>
#include <cstdint>
#include <cstddef>
#include <math.h>

#define SEQ    2048
#define NBATCH 4
#define DIN    1024
#define DH     64

typedef __attribute__((ext_vector_type(8))) short  short8;   // 8 x bf16 (4 VGPRs)
typedef __attribute__((ext_vector_type(4))) float  floatx4;  // MFMA C/D

#define MFMA16(a, b, c) __builtin_amdgcn_mfma_f32_16x16x32_bf16((a), (b), (c), 0, 0, 0)

__device__ __forceinline__ unsigned short f2bf(float x) {
  unsigned u = __float_as_uint(x);
  return (unsigned short)((u + 0x8000u) >> 16);   // round-half-up; values finite
}
__device__ __forceinline__ float bf2f(unsigned short h) {
  return __uint_as_float(((unsigned)h) << 16);
}

// ======================= host-side numpy RNG replication =======================
namespace nprng {

struct PCG64 {
  __uint128_t state, inc;
  bool has_uint32;
  uint32_t uinteger;
};

static inline void pcg_step(PCG64 &g) {
  const __uint128_t MULT =
      (((__uint128_t)0x2360ed051fc65da4ULL) << 64) | 0x4385df649fccf645ULL;
  g.state = g.state * MULT + g.inc;
}

static inline uint64_t pcg_output(const PCG64 &g) {
  uint64_t hi = (uint64_t)(g.state >> 64);
  uint64_t lo = (uint64_t)g.state;
  uint64_t x = hi ^ lo;
  unsigned rot = (unsigned)(g.state >> 122) & 63u;
  return (x >> rot) | (x << ((64u - rot) & 63u));
}

static inline uint64_t pcg_next64(PCG64 &g) { pcg_step(g); return pcg_output(g); }

static inline uint32_t pcg_next32(PCG64 &g) {
  if (g.has_uint32) { g.has_uint32 = false; return g.uinteger; }
  uint64_t n = pcg_next64(g);
  g.has_uint32 = true;
  g.uinteger = (uint32_t)(n >> 32);
  return (uint32_t)(n & 0xffffffffu);
}

static inline void pcg_seed_from_seedseq0(PCG64 &g) {
  const uint32_t MULT_A = 0x931e8875u;
  const uint32_t MULT_B = 0x58f38dedu;
  const uint32_t MIX_L  = 0xca01f9ddu;
  const uint32_t MIX_R  = 0x4973f715u;
  uint32_t hc = 0x43b0d7e5u;  // INIT_A
  uint32_t pool[4];
  for (int i = 0; i < 4; i++) {
    uint32_t v = 0u;
    v ^= hc; hc *= MULT_A; v *= hc; v ^= v >> 16;
    pool[i] = v;
  }
  for (int is = 0; is < 4; is++) {
    for (int id = 0; id < 4; id++) {
      if (is == id) continue;
      uint32_t h = pool[is];
      h ^= hc; hc *= MULT_A; h *= hc; h ^= h >> 16;
      uint32_t r = (pool[id] * MIX_L) ^ (h * MIX_R);
      r ^= r >> 16;
      pool[id] = r;
    }
  }
  uint32_t hb = 0x8b51f9ddu;  // INIT_B
  uint32_t w[8];
  for (int i = 0; i < 8; i++) {
    uint32_t v = pool[i & 3];
    v ^= hb; hb *= MULT_B; v *= hb; v ^= v >> 16;
    w[i] = v;
  }
  uint64_t sv[4];
  for (int k = 0; k < 4; k++)
    sv[k] = (uint64_t)w[2 * k] | ((uint64_t)w[2 * k + 1] << 32);
  __uint128_t initstate = (((__uint128_t)sv[0]) << 64) | sv[1];
  __uint128_t initseq   = (((__uint128_t)sv[2]) << 64) | sv[3];
  g.state = 0; g.inc = (initseq << 1) | 1;
  pcg_step(g);
  g.state += initstate;
  pcg_step(g);
  g.has_uint32 = false; g.uinteger = 0;
}

static inline uint32_t bounded32(PCG64 &g, uint32_t rng /*inclusive max*/) {
  if (rng == 0) return 0;
  const uint32_t rng_excl = rng + 1u;
  uint64_t m = (uint64_t)pcg_next32(g) * (uint64_t)rng_excl;
  uint32_t leftover = (uint32_t)m;
  if (leftover < rng_excl) {
    const uint32_t threshold = (uint32_t)(0xffffffffu - rng) % rng_excl;
    while (leftover < threshold) {
      m = (uint64_t)pcg_next32(g) * (uint64_t)rng_excl;
      leftover = (uint32_t)m;
    }
  }
  return (uint32_t)(m >> 32);
}

static inline void choice3_2048(PCG64 &g, long long idx[3]) {
  const int pop = 2048, sz = 3;
  uint64_t hs[4] = { (uint64_t)-1, (uint64_t)-1, (uint64_t)-1, (uint64_t)-1 };
  const uint64_t mask = 3;
  for (int j = pop - sz; j < pop; j++) {
    uint64_t val = (uint64_t)bounded32(g, (uint32_t)j);
    uint64_t loc = val & mask;
    while (hs[loc] != (uint64_t)-1 && hs[loc] != val) loc = (loc + 1) & mask;
    if (hs[loc] == (uint64_t)-1) {
      hs[loc] = val;
      idx[j - pop + sz] = (long long)val;
    } else {
      loc = (uint64_t)j & mask;
      while (hs[loc] != (uint64_t)-1) loc = (loc + 1) & mask;
      hs[loc] = (uint64_t)j;
      idx[j - pop + sz] = (long long)j;
    }
  }
  for (int i = 2; i >= 1; i--) {
    uint32_t j = bounded32(g, (uint32_t)i);
    long long t = idx[j]; idx[j] = idx[i]; idx[i] = t;
  }
}

}  // namespace nprng

// ==================== kernel 0: W -> W^T bf16 (tiny, once) ====================
// WT layout: [proj][n=64][k=1024] bf16.
__global__ __launch_bounds__(256) void wtrans_kernel(
    const float* __restrict__ Wq, const float* __restrict__ Wk,
    const float* __restrict__ Wv, unsigned short* __restrict__ WT) {
  int idx = blockIdx.x * 256 + threadIdx.x;     // 0 .. 3*64*1024-1
  int p   = idx >> 16;
  int rem = idx & 65535;
  int n   = rem >> 10;
  int k   = rem & 1023;
  const float* W = (p == 0) ? Wq : (p == 1) ? Wk : Wv;
  WT[idx] = f2bf(W[k * 64 + n]);
}

// ===================== projections: bf16 MFMA, LDS-free loop ==================
// grid (256, 3), 128 threads (2 waves). Block = 32 seq-rows, full 64 out-dims.
// Wave w owns rows m0+16w..+15. A-frags: straight global fp32 -> bf16 cvt.
// B-frags: straight global from WT (L2-resident). No barriers in K-loop.
__global__ __launch_bounds__(128, 2) void proj_kernel(
    const float* __restrict__ xq, const float* __restrict__ xk,
    const float* __restrict__ xv, const unsigned short* __restrict__ WT,
    const float* __restrict__ bq, const float* __restrict__ bk,
    const float* __restrict__ bv,
    unsigned short* __restrict__ QP, unsigned short* __restrict__ KP,
    unsigned short* __restrict__ VPT) {
  const int proj = blockIdx.y;
  const float* X    = (proj == 0) ? xq : (proj == 1) ? xk : xv;
  const float* bias = (proj == 0) ? bq : (proj == 1) ? bk : bv;

  const int m0   = blockIdx.x * 32;
  const int tid  = threadIdx.x;
  const int w    = tid >> 6;
  const int l    = tid & 63;
  const int quad = l >> 4;
  const int lx   = l & 15;

  const float* Xr = X + (size_t)(m0 + 16 * w + lx) * DIN + quad * 8;
  const unsigned short* Wt_p = WT + (size_t)proj * 64 * 1024 + quad * 8;
  const unsigned short* Wr0 = Wt_p + (size_t)(lx)      * 1024;
  const unsigned short* Wr1 = Wt_p + (size_t)(16 + lx) * 1024;
  const unsigned short* Wr2 = Wt_p + (size_t)(32 + lx) * 1024;
  const unsigned short* Wr3 = Wt_p + (size_t)(48 + lx) * 1024;

  floatx4 acc0 = {0.f, 0.f, 0.f, 0.f}, acc1 = acc0, acc2 = acc0, acc3 = acc0;

  float4 xc0 = *(const float4*)(Xr);
  float4 xc1 = *(const float4*)(Xr + 4);
  short8 wc0 = *(const short8*)(Wr0);
  short8 wc1 = *(const short8*)(Wr1);
  short8 wc2 = *(const short8*)(Wr2);
  short8 wc3 = *(const short8*)(Wr3);

  for (int k = 32; k < DIN; k += 32) {
    float4 xn0 = *(const float4*)(Xr + k);
    float4 xn1 = *(const float4*)(Xr + k + 4);
    short8 wn0 = *(const short8*)(Wr0 + k);
    short8 wn1 = *(const short8*)(Wr1 + k);
    short8 wn2 = *(const short8*)(Wr2 + k);
    short8 wn3 = *(const short8*)(Wr3 + k);
    short8 af;
    af[0] = f2bf(xc0.x); af[1] = f2bf(xc0.y); af[2] = f2bf(xc0.z); af[3] = f2bf(xc0.w);
    af[4] = f2bf(xc1.x); af[5] = f2bf(xc1.y); af[6] = f2bf(xc1.z); af[7] = f2bf(xc1.w);
    acc0 = MFMA16(af, wc0, acc0);
    acc1 = MFMA16(af, wc1, acc1);
    acc2 = MFMA16(af, wc2, acc2);
    acc3 = MFMA16(af, wc3, acc3);
    xc0 = xn0; xc1 = xn1; wc0 = wn0; wc1 = wn1; wc2 = wn2; wc3 = wn3;
  }
  {
    short8 af;
    af[0] = f2bf(xc0.x); af[1] = f2bf(xc0.y); af[2] = f2bf(xc0.z); af[3] = f2bf(xc0.w);
    af[4] = f2bf(xc1.x); af[5] = f2bf(xc1.y); af[6] = f2bf(xc1.z); af[7] = f2bf(xc1.w);
    acc0 = MFMA16(af, wc0, acc0);
    acc1 = MFMA16(af, wc1, acc1);
    acc2 = MFMA16(af, wc2, acc2);
    acc3 = MFMA16(af, wc3, acc3);
  }

  // epilogue: C-frags (+bias) -> LDS -> coalesced bf16 writes
  __shared__ float Cs[32][72];
  float b0 = bias[lx], b1 = bias[16 + lx], b2 = bias[32 + lx], b3 = bias[48 + lx];
#pragma unroll
  for (int i = 0; i < 4; i++) {
    const int r = 16 * w + quad * 4 + i;
    Cs[r][lx]      = acc0[i] + b0;
    Cs[r][16 + lx] = acc1[i] + b1;
    Cs[r][32 + lx] = acc2[i] + b2;
    Cs[r][48 + lx] = acc3[i] + b3;
  }
  __syncthreads();

  if (proj < 2) {
    unsigned short* outp = (proj == 0) ? QP : KP;
    const int row = tid >> 2;            // 0..31
    const int d0  = (tid & 3) * 16;      // 0,16,32,48
    short8 v0, v1;
#pragma unroll
    for (int j = 0; j < 8; j++) v0[j] = (short)f2bf(Cs[row][d0 + j]);
#pragma unroll
    for (int j = 0; j < 8; j++) v1[j] = (short)f2bf(Cs[row][d0 + 8 + j]);
    unsigned short* dst = outp + (size_t)(m0 + row) * 64 + d0;
    *(short8*)dst = v0;
    *((short8*)dst + 1) = v1;
  } else {
    // V transposed: VPT[b*64 + dim][2048]
    const int dim = tid >> 1;            // 0..63
    const int s0  = (tid & 1) * 16;      // 0,16
    const int bq_ = m0 >> 11;            // batch
    const int sq  = (m0 & 2047) + s0;
    short8 v0, v1;
#pragma unroll
    for (int j = 0; j < 8; j++) v0[j] = (short)f2bf(Cs[s0 + j][dim]);
#pragma unroll
    for (int j = 0; j < 8; j++) v1[j] = (short)f2bf(Cs[s0 + 8 + j][dim]);
    unsigned short* dst = VPT + ((size_t)bq_ * 64 + dim) * SEQ + sq;
    *(short8*)dst = v0;
    *((short8*)dst + 1) = v1;
  }
}

// ===================== flash attention: bf16 MFMA, 1 barrier ==================
// grid (128, 4), 256 threads (4 waves). Block = 16 q-rows; wave w processes
// key-tiles t = w, w+4, ... with an independent online-softmax state; states
// merged once at the end. K/V^T fragments straight from global (L2-resident),
// double-buffered. P transits per-wave LDS for C-layout -> A-layout.
__global__ __launch_bounds__(256, 2) void attn_kernel(
    const unsigned short* __restrict__ QP, const unsigned short* __restrict__ KP,
    const unsigned short* __restrict__ VPT, float* __restrict__ out,
    int R0, int C0, int R1, int C1, int R2, int C2) {
  const int b    = blockIdx.y;
  const int q0   = blockIdx.x * 16;
  const int tid  = threadIdx.x;
  const int w    = tid >> 6;
  const int l    = tid & 63;
  const int quad = l >> 4;
  const int lx   = l & 15;

  __shared__ unsigned short Ps[4][16][72];
  __shared__ float Os[4][16][64];
  __shared__ float mS[4][16], lS[4][16];
  __shared__ float lgS[3];
  __shared__ int   lgF[3];

  const unsigned short* Qb = QP + ((size_t)b * SEQ + q0) * 64;
  const unsigned short* Kb = KP + (size_t)b * SEQ * 64;
  const unsigned short* Vb = VPT + (size_t)b * 64 * SEQ;

  const short8 aq0 = *(const short8*)(Qb + (size_t)lx * 64 + quad * 8);
  const short8 aq1 = *(const short8*)(Qb + (size_t)lx * 64 + 32 + quad * 8);

  floatx4 O[4];
  float m_i[4], l_i[4];
#pragma unroll
  for (int c = 0; c < 4; c++) O[c] = (floatx4){0.f, 0.f, 0.f, 0.f};
#pragma unroll
  for (int i = 0; i < 4; i++) { m_i[i] = -INFINITY; l_i[i] = 0.f; }

  const int T = (q0 + 16 + 63) >> 6;   // key-tiles needed (64 keys each)

  auto loadTile = [&](int t, short8 kf[8], short8 vf[8]) {
    const int k0 = t << 6;
#pragma unroll
    for (int c = 0; c < 4; c++) {
#pragma unroll
      for (int s = 0; s < 2; s++) {
        kf[c * 2 + s] = *(const short8*)(Kb + (size_t)(k0 + 16 * c + lx) * 64 + s * 32 + quad * 8);
        vf[s * 4 + c] = *(const short8*)(Vb + (size_t)(16 * c + lx) * SEQ + k0 + s * 32 + quad * 8);
      }
    }
  };

  auto computeTile = [&](int t, const short8 kf[8], const short8 vf[8]) {
    const int k0 = t << 6;
    const bool mT = (t == T - 1);
    floatx4 sc[4];
#pragma unroll
    for (int c = 0; c < 4; c++) {
      sc[c] = (floatx4){0.f, 0.f, 0.f, 0.f};
      sc[c] = MFMA16(aq0, kf[2 * c], sc[c]);
      sc[c] = MFMA16(aq1, kf[2 * c + 1], sc[c]);
    }
    float mt[4], al[4];
#pragma unroll
    for (int i = 0; i < 4; i++) {
      const int rowg = q0 + quad * 4 + i;
      float vmax = -INFINITY;
#pragma unroll
      for (int c = 0; c < 4; c++) {
        float v = sc[c][i] * 0.125f;
        if (mT && (k0 + 16 * c + lx) > rowg) v = -INFINITY;
        sc[c][i] = v;
        vmax = fmaxf(vmax, v);
      }
      mt[i] = vmax;
    }
#pragma unroll
    for (int i = 0; i < 4; i++) {
#pragma unroll
      for (int off = 8; off >= 1; off >>= 1)
        mt[i] = fmaxf(mt[i], __shfl_xor(mt[i], off));
      const float mn = fmaxf(m_i[i], mt[i]);
      al[i] = __expf(m_i[i] - mn);
      m_i[i] = mn;
      float s = 0.f;
#pragma unroll
      for (int c = 0; c < 4; c++) {
        float p = __expf(sc[c][i] - mn);
        Ps[w][quad * 4 + i][16 * c + lx] = f2bf(p);
        s += p;
      }
#pragma unroll
      for (int off = 8; off >= 1; off >>= 1) s += __shfl_xor(s, off);
      l_i[i] = l_i[i] * al[i] + s;
    }
#pragma unroll
    for (int c = 0; c < 4; c++)
#pragma unroll
      for (int i = 0; i < 4; i++) O[c][i] *= al[i];
    asm volatile("" ::: "memory");  // keep ds_reads below the ds_writes above
    const short8 pf0 = *(const short8*)&Ps[w][lx][quad * 8];
    const short8 pf1 = *(const short8*)&Ps[w][lx][32 + quad * 8];
#pragma unroll
    for (int c = 0; c < 4; c++) {
      O[c] = MFMA16(pf0, vf[c],     O[c]);
      O[c] = MFMA16(pf1, vf[4 + c], O[c]);
    }
  };

  short8 kA[8], vA[8], kB[8], vB[8];
  int t = w;
  if (t < T) loadTile(t, kA, vA);
  while (t < T) {
    int tn = t + 4;
    if (tn < T) loadTile(tn, kB, vB);
    computeTile(t, kA, vA);
    t = tn;
    if (t >= T) break;
    tn = t + 4;
    if (tn < T) loadTile(tn, kA, vA);
    computeTile(t, kB, vB);
    t = tn;
  }

  // deposit per-wave state
  if (lx == 0) {
#pragma unroll
    for (int i = 0; i < 4; i++) {
      mS[w][quad * 4 + i] = m_i[i];
      lS[w][quad * 4 + i] = l_i[i];
    }
  }
#pragma unroll
  for (int c = 0; c < 4; c++)
#pragma unroll
    for (int i = 0; i < 4; i++) Os[w][quad * 4 + i][16 * c + lx] = O[c][i];

  // wave 0: logits for global pairs above the diagonal
  if (w == 0) {
#pragma unroll
    for (int p = 0; p < 3; p++) {
      const int R = (p == 0) ? R0 : (p == 1) ? R1 : R2;
      const int C = (p == 0) ? C0 : (p == 1) ? C1 : C2;
      const int act = (R >= q0 && R < q0 + 16 && C > R);
      float d = 0.f;
      if (act) {
        const float qv = bf2f(QP[((size_t)b * SEQ + R) * 64 + l]);
        const float kv = bf2f(KP[((size_t)b * SEQ + C) * 64 + l]);
        d = qv * kv;
#pragma unroll
        for (int off = 32; off >= 1; off >>= 1) d += __shfl_xor(d, off);
        d *= 0.125f;
      }
      if (l == 0) { lgF[p] = act; lgS[p] = d; }
    }
  }
  __syncthreads();

  // merge the 4 wave states (+ pair fixups), normalize, store
  {
    const int row = tid >> 4;          // 0..15
    const int d0  = (tid & 15) * 4;    // 0..60
    const int Rs[3] = {R0, R1, R2};
    const int Cs3[3] = {C0, C1, C2};

    float mf = -INFINITY;
#pragma unroll
    for (int w4 = 0; w4 < 4; w4++) mf = fmaxf(mf, mS[w4][row]);
#pragma unroll
    for (int p = 0; p < 3; p++)
      if (lgF[p] && (Rs[p] - q0) == row) mf = fmaxf(mf, lgS[p]);

    float lf = 0.f;
    float o0 = 0.f, o1 = 0.f, o2 = 0.f, o3 = 0.f;
#pragma unroll
    for (int w4 = 0; w4 < 4; w4++) {
      const float a = __expf(mS[w4][row] - mf);
      lf += a * lS[w4][row];
      const float* op = &Os[w4][row][d0];
      o0 += a * op[0]; o1 += a * op[1]; o2 += a * op[2]; o3 += a * op[3];
    }
#pragma unroll
    for (int p = 0; p < 3; p++) {
      if (lgF[p] && (Rs[p] - q0) == row) {
        const float pe = __expf(lgS[p] - mf);
        lf += pe;
        const int C = Cs3[p];
        o0 += pe * bf2f(Vb[(size_t)(d0 + 0) * SEQ + C]);
        o1 += pe * bf2f(Vb[(size_t)(d0 + 1) * SEQ + C]);
        o2 += pe * bf2f(Vb[(size_t)(d0 + 2) * SEQ + C]);
        o3 += pe * bf2f(Vb[(size_t)(d0 + 3) * SEQ + C]);
      }
    }
    const float inv = 1.0f / lf;
    float4 r;
    r.x = o0 * inv; r.y = o1 * inv; r.z = o2 * inv; r.w = o3 * inv;
    *(float4*)(out + ((size_t)b * SEQ + q0 + row) * 64 + d0) = r;
  }
}

// ================================= launch =====================================
extern "C" void kernel_launch(void* const* d_in, const int* in_sizes, int n_in,
                              void* d_out, int out_size, void* d_ws,
                              size_t ws_size, hipStream_t stream) {
  const float* xq = (const float*)d_in[0];
  const float* xk = (const float*)d_in[1];
  const float* xv = (const float*)d_in[2];
  const float* Wq = (const float*)d_in[3];
  const float* bq = (const float*)d_in[4];
  const float* Wk = (const float*)d_in[5];
  const float* bk = (const float*)d_in[6];
  const float* Wv = (const float*)d_in[7];
  const float* bv = (const float*)d_in[8];
  float* out = (float*)d_out;

  // workspace (bf16): QP 1MB, KP 1MB, VPT 1MB, WT 384KB
  unsigned short* QP  = (unsigned short*)d_ws;
  unsigned short* KP  = QP + (size_t)NBATCH * SEQ * 64;
  unsigned short* VPT = KP + (size_t)NBATCH * SEQ * 64;
  unsigned short* WT  = VPT + (size_t)NBATCH * 64 * SEQ;

  nprng::PCG64 g;
  nprng::pcg_seed_from_seedseq0(g);
  long long rows[3], cols[3];
  nprng::choice3_2048(g, rows);
  nprng::choice3_2048(g, cols);

  wtrans_kernel<<<768, 256, 0, stream>>>(Wq, Wk, Wv, WT);

  dim3 pgrid(256, 3);
  proj_kernel<<<pgrid, 128, 0, stream>>>(xq, xk, xv, WT, bq, bk, bv, QP, KP, VPT);

  dim3 agrid(SEQ / 16, NBATCH);
  attn_kernel<<<agrid, 256, 0, stream>>>(
      QP, KP, VPT, out, (int)rows[0], (int)cols[0], (int)rows[1], (int)cols[1],
      (int)rows[2], (int)cols[2]);
}

// Round 3
// 188.450 us; speedup vs baseline: 2.1001x; 1.0115x over previous
//
#include <hip/hip_runtime.h>
#include <cstdint>
#include <cstddef>
#include <math.h>

#define SEQ    2048
#define NBATCH 4
#define DIN    1024
#define DH     64

typedef __attribute__((ext_vector_type(8))) short  short8;   // 8 x bf16 (4 VGPRs)
typedef __attribute__((ext_vector_type(4))) float  floatx4;  // MFMA C/D
typedef __attribute__((ext_vector_type(4))) unsigned short ushort4v;

#define MFMA16(a, b, c) __builtin_amdgcn_mfma_f32_16x16x32_bf16((a), (b), (c), 0, 0, 0)

__device__ __forceinline__ unsigned short f2bf(float x) {
  unsigned u = __float_as_uint(x);
  return (unsigned short)((u + 0x8000u) >> 16);   // round-half-up; values finite
}
__device__ __forceinline__ float bf2f(unsigned short h) {
  return __uint_as_float(((unsigned)h) << 16);
}

// ======================= host-side numpy RNG replication =======================
namespace nprng {

struct PCG64 {
  __uint128_t state, inc;
  bool has_uint32;
  uint32_t uinteger;
};

static inline void pcg_step(PCG64 &g) {
  const __uint128_t MULT =
      (((__uint128_t)0x2360ed051fc65da4ULL) << 64) | 0x4385df649fccf645ULL;
  g.state = g.state * MULT + g.inc;
}

static inline uint64_t pcg_output(const PCG64 &g) {
  uint64_t hi = (uint64_t)(g.state >> 64);
  uint64_t lo = (uint64_t)g.state;
  uint64_t x = hi ^ lo;
  unsigned rot = (unsigned)(g.state >> 122) & 63u;
  return (x >> rot) | (x << ((64u - rot) & 63u));
}

static inline uint64_t pcg_next64(PCG64 &g) { pcg_step(g); return pcg_output(g); }

static inline uint32_t pcg_next32(PCG64 &g) {
  if (g.has_uint32) { g.has_uint32 = false; return g.uinteger; }
  uint64_t n = pcg_next64(g);
  g.has_uint32 = true;
  g.uinteger = (uint32_t)(n >> 32);
  return (uint32_t)(n & 0xffffffffu);
}

static inline void pcg_seed_from_seedseq0(PCG64 &g) {
  const uint32_t MULT_A = 0x931e8875u;
  const uint32_t MULT_B = 0x58f38dedu;
  const uint32_t MIX_L  = 0xca01f9ddu;
  const uint32_t MIX_R  = 0x4973f715u;
  uint32_t hc = 0x43b0d7e5u;  // INIT_A
  uint32_t pool[4];
  for (int i = 0; i < 4; i++) {
    uint32_t v = 0u;
    v ^= hc; hc *= MULT_A; v *= hc; v ^= v >> 16;
    pool[i] = v;
  }
  for (int is = 0; is < 4; is++) {
    for (int id = 0; id < 4; id++) {
      if (is == id) continue;
      uint32_t h = pool[is];
      h ^= hc; hc *= MULT_A; h *= hc; h ^= h >> 16;
      uint32_t r = (pool[id] * MIX_L) ^ (h * MIX_R);
      r ^= r >> 16;
      pool[id] = r;
    }
  }
  uint32_t hb = 0x8b51f9ddu;  // INIT_B
  uint32_t w[8];
  for (int i = 0; i < 8; i++) {
    uint32_t v = pool[i & 3];
    v ^= hb; hb *= MULT_B; v *= hb; v ^= v >> 16;
    w[i] = v;
  }
  uint64_t sv[4];
  for (int k = 0; k < 4; k++)
    sv[k] = (uint64_t)w[2 * k] | ((uint64_t)w[2 * k + 1] << 32);
  __uint128_t initstate = (((__uint128_t)sv[0]) << 64) | sv[1];
  __uint128_t initseq   = (((__uint128_t)sv[2]) << 64) | sv[3];
  g.state = 0; g.inc = (initseq << 1) | 1;
  pcg_step(g);
  g.state += initstate;
  pcg_step(g);
  g.has_uint32 = false; g.uinteger = 0;
}

static inline uint32_t bounded32(PCG64 &g, uint32_t rng /*inclusive max*/) {
  if (rng == 0) return 0;
  const uint32_t rng_excl = rng + 1u;
  uint64_t m = (uint64_t)pcg_next32(g) * (uint64_t)rng_excl;
  uint32_t leftover = (uint32_t)m;
  if (leftover < rng_excl) {
    const uint32_t threshold = (uint32_t)(0xffffffffu - rng) % rng_excl;
    while (leftover < threshold) {
      m = (uint64_t)pcg_next32(g) * (uint64_t)rng_excl;
      leftover = (uint32_t)m;
    }
  }
  return (uint32_t)(m >> 32);
}

static inline void choice3_2048(PCG64 &g, long long idx[3]) {
  const int pop = 2048, sz = 3;
  uint64_t hs[4] = { (uint64_t)-1, (uint64_t)-1, (uint64_t)-1, (uint64_t)-1 };
  const uint64_t mask = 3;
  for (int j = pop - sz; j < pop; j++) {
    uint64_t val = (uint64_t)bounded32(g, (uint32_t)j);
    uint64_t loc = val & mask;
    while (hs[loc] != (uint64_t)-1 && hs[loc] != val) loc = (loc + 1) & mask;
    if (hs[loc] == (uint64_t)-1) {
      hs[loc] = val;
      idx[j - pop + sz] = (long long)val;
    } else {
      loc = (uint64_t)j & mask;
      while (hs[loc] != (uint64_t)-1) loc = (loc + 1) & mask;
      hs[loc] = (uint64_t)j;
      idx[j - pop + sz] = (long long)j;
    }
  }
  for (int i = 2; i >= 1; i--) {
    uint32_t j = bounded32(g, (uint32_t)i);
    long long t = idx[j]; idx[j] = idx[i]; idx[i] = t;
  }
}

}  // namespace nprng

// ==================== kernel 0: W -> W^T bf16 (tiny, once) ====================
// WT layout: [proj][n=64][k=1024] bf16.
__global__ __launch_bounds__(256) void wtrans_kernel(
    const float* __restrict__ Wq, const float* __restrict__ Wk,
    const float* __restrict__ Wv, unsigned short* __restrict__ WT) {
  int idx = blockIdx.x * 256 + threadIdx.x;     // 0 .. 3*64*1024-1
  int p   = idx >> 16;
  int rem = idx & 65535;
  int n   = rem >> 10;
  int k   = rem & 1023;
  const float* W = (p == 0) ? Wq : (p == 1) ? Wk : Wv;
  WT[idx] = f2bf(W[k * 64 + n]);
}

// ================= projections: bf16 MFMA, K-split over 4 waves ===============
// grid (512, 3), 256 threads (4 waves). Block = 16 seq-rows, full 64 out-dims.
// Wave w handles K range [256w, 256w+256); partials reduced through LDS.
__global__ __launch_bounds__(256, 4) void proj_kernel(
    const float* __restrict__ xq, const float* __restrict__ xk,
    const float* __restrict__ xv, const unsigned short* __restrict__ WT,
    const float* __restrict__ bq, const float* __restrict__ bk,
    const float* __restrict__ bv,
    unsigned short* __restrict__ QP, unsigned short* __restrict__ KP,
    unsigned short* __restrict__ VPT) {
  const int proj = blockIdx.y;
  const float* X    = (proj == 0) ? xq : (proj == 1) ? xk : xv;
  const float* bias = (proj == 0) ? bq : (proj == 1) ? bk : bv;

  const int m0   = blockIdx.x * 16;
  const int tid  = threadIdx.x;
  const int w    = tid >> 6;
  const int l    = tid & 63;
  const int quad = l >> 4;
  const int lx   = l & 15;
  const int kb   = w << 8;            // 0,256,512,768

  const float* Xr = X + (size_t)(m0 + lx) * DIN + kb + quad * 8;
  const unsigned short* Wb = WT + (size_t)proj * 65536 + kb + quad * 8;
  const unsigned short* Wr0 = Wb + (size_t)(lx)      * 1024;
  const unsigned short* Wr1 = Wb + (size_t)(16 + lx) * 1024;
  const unsigned short* Wr2 = Wb + (size_t)(32 + lx) * 1024;
  const unsigned short* Wr3 = Wb + (size_t)(48 + lx) * 1024;

  floatx4 acc0 = {0.f, 0.f, 0.f, 0.f}, acc1 = acc0, acc2 = acc0, acc3 = acc0;

  float4 xc0 = *(const float4*)(Xr);
  float4 xc1 = *(const float4*)(Xr + 4);
  short8 wc0 = *(const short8*)(Wr0);
  short8 wc1 = *(const short8*)(Wr1);
  short8 wc2 = *(const short8*)(Wr2);
  short8 wc3 = *(const short8*)(Wr3);

  for (int k = 32; k < 256; k += 32) {
    float4 xn0 = *(const float4*)(Xr + k);
    float4 xn1 = *(const float4*)(Xr + k + 4);
    short8 wn0 = *(const short8*)(Wr0 + k);
    short8 wn1 = *(const short8*)(Wr1 + k);
    short8 wn2 = *(const short8*)(Wr2 + k);
    short8 wn3 = *(const short8*)(Wr3 + k);
    short8 af;
    af[0] = f2bf(xc0.x); af[1] = f2bf(xc0.y); af[2] = f2bf(xc0.z); af[3] = f2bf(xc0.w);
    af[4] = f2bf(xc1.x); af[5] = f2bf(xc1.y); af[6] = f2bf(xc1.z); af[7] = f2bf(xc1.w);
    acc0 = MFMA16(af, wc0, acc0);
    acc1 = MFMA16(af, wc1, acc1);
    acc2 = MFMA16(af, wc2, acc2);
    acc3 = MFMA16(af, wc3, acc3);
    xc0 = xn0; xc1 = xn1; wc0 = wn0; wc1 = wn1; wc2 = wn2; wc3 = wn3;
  }
  {
    short8 af;
    af[0] = f2bf(xc0.x); af[1] = f2bf(xc0.y); af[2] = f2bf(xc0.z); af[3] = f2bf(xc0.w);
    af[4] = f2bf(xc1.x); af[5] = f2bf(xc1.y); af[6] = f2bf(xc1.z); af[7] = f2bf(xc1.w);
    acc0 = MFMA16(af, wc0, acc0);
    acc1 = MFMA16(af, wc1, acc1);
    acc2 = MFMA16(af, wc2, acc2);
    acc3 = MFMA16(af, wc3, acc3);
  }

  // partial-sum reduce across waves through LDS
  __shared__ float Cs[4][16][68];   // [wave][row][dim], pad 68 kills conflicts
#pragma unroll
  for (int i = 0; i < 4; i++) {
    const int r = quad * 4 + i;
    Cs[w][r][lx]      = acc0[i];
    Cs[w][r][16 + lx] = acc1[i];
    Cs[w][r][32 + lx] = acc2[i];
    Cs[w][r][48 + lx] = acc3[i];
  }
  __syncthreads();

  if (proj < 2) {
    unsigned short* outp = (proj == 0) ? QP : KP;
    const int row = tid >> 4;            // 0..15
    const int d0  = (tid & 15) * 4;      // 0..60
    ushort4v v;
#pragma unroll
    for (int j = 0; j < 4; j++) {
      float s = Cs[0][row][d0 + j] + Cs[1][row][d0 + j] +
                Cs[2][row][d0 + j] + Cs[3][row][d0 + j] + bias[d0 + j];
      v[j] = f2bf(s);
    }
    *(ushort4v*)(outp + (size_t)(m0 + row) * 64 + d0) = v;
  } else {
    // V transposed: VPT[b*64 + dim][2048]
    const int dim = tid >> 2;            // 0..63
    const int s0  = (tid & 3) * 4;       // 0,4,8,12
    const int bq_ = m0 >> 11;            // batch
    const int sq  = (m0 & 2047) + s0;
    const float bb = bias[dim];
    ushort4v v;
#pragma unroll
    for (int j = 0; j < 4; j++) {
      float s = Cs[0][s0 + j][dim] + Cs[1][s0 + j][dim] +
                Cs[2][s0 + j][dim] + Cs[3][s0 + j][dim] + bb;
      v[j] = f2bf(s);
    }
    *(ushort4v*)(VPT + ((size_t)bq_ * 64 + dim) * SEQ + sq) = v;
  }
}

// ===================== flash attention: bf16 MFMA, 1 barrier ==================
// grid (128, 4), 256 threads (4 waves). Block = 16 q-rows; wave w processes
// key-tiles t = w, w+4, ... with independent online-softmax state; merged once.
// Single-buffered fragments (spill-safe). q-tiles pair-complemented so
// co-resident blocks have ~equal causal work.
__global__ __launch_bounds__(256, 2) void attn_kernel(
    const unsigned short* __restrict__ QP, const unsigned short* __restrict__ KP,
    const unsigned short* __restrict__ VPT, float* __restrict__ out,
    int R0, int C0, int R1, int C1, int R2, int C2) {
  const int b    = blockIdx.y;
  const int bx   = blockIdx.x;
  const int qi   = (bx & 1) ? (127 - (bx >> 1)) : (bx >> 1);  // heavy/light pairing
  const int q0   = qi * 16;
  const int tid  = threadIdx.x;
  const int w    = tid >> 6;
  const int l    = tid & 63;
  const int quad = l >> 4;
  const int lx   = l & 15;

  __shared__ unsigned short Ps[4][16][72];
  __shared__ float Os[4][16][64];
  __shared__ float mS[4][16], lS[4][16];
  __shared__ float lgS[3];
  __shared__ int   lgF[3];

  const unsigned short* Qb = QP + ((size_t)b * SEQ + q0) * 64;
  const unsigned short* Kb = KP + (size_t)b * SEQ * 64;
  const unsigned short* Vb = VPT + (size_t)b * 64 * SEQ;

  const short8 aq0 = *(const short8*)(Qb + (size_t)lx * 64 + quad * 8);
  const short8 aq1 = *(const short8*)(Qb + (size_t)lx * 64 + 32 + quad * 8);

  floatx4 O[4];
  float m_i[4], l_i[4];
#pragma unroll
  for (int c = 0; c < 4; c++) O[c] = (floatx4){0.f, 0.f, 0.f, 0.f};
#pragma unroll
  for (int i = 0; i < 4; i++) { m_i[i] = -INFINITY; l_i[i] = 0.f; }

  const int T = (q0 + 79) >> 6;   // key-tiles needed (64 keys each)

  for (int t = w; t < T; t += 4) {
    const int k0 = t << 6;
    const bool mT = (t == T - 1);

    short8 kf[8], vf[8];
#pragma unroll
    for (int c = 0; c < 4; c++) {
#pragma unroll
      for (int s = 0; s < 2; s++) {
        kf[c * 2 + s] = *(const short8*)(Kb + (size_t)(k0 + 16 * c + lx) * 64 + s * 32 + quad * 8);
        vf[s * 4 + c] = *(const short8*)(Vb + (size_t)(16 * c + lx) * SEQ + k0 + s * 32 + quad * 8);
      }
    }

    floatx4 sc[4];
#pragma unroll
    for (int c = 0; c < 4; c++) {
      sc[c] = (floatx4){0.f, 0.f, 0.f, 0.f};
      sc[c] = MFMA16(aq0, kf[2 * c], sc[c]);
      sc[c] = MFMA16(aq1, kf[2 * c + 1], sc[c]);
    }

    float mt[4], al[4];
#pragma unroll
    for (int i = 0; i < 4; i++) {
      const int rowg = q0 + quad * 4 + i;
      float vmax = -INFINITY;
#pragma unroll
      for (int c = 0; c < 4; c++) {
        float v = sc[c][i] * 0.125f;
        if (mT && (k0 + 16 * c + lx) > rowg) v = -INFINITY;
        sc[c][i] = v;
        vmax = fmaxf(vmax, v);
      }
      mt[i] = vmax;
    }
#pragma unroll
    for (int i = 0; i < 4; i++) {
#pragma unroll
      for (int off = 8; off >= 1; off >>= 1)
        mt[i] = fmaxf(mt[i], __shfl_xor(mt[i], off));
      const float mn = fmaxf(m_i[i], mt[i]);
      al[i] = __expf(m_i[i] - mn);
      m_i[i] = mn;
      float s = 0.f;
#pragma unroll
      for (int c = 0; c < 4; c++) {
        float p = __expf(sc[c][i] - mn);
        Ps[w][quad * 4 + i][16 * c + lx] = f2bf(p);
        s += p;
      }
#pragma unroll
      for (int off = 8; off >= 1; off >>= 1) s += __shfl_xor(s, off);
      l_i[i] = l_i[i] * al[i] + s;
    }
#pragma unroll
    for (int c = 0; c < 4; c++)
#pragma unroll
      for (int i = 0; i < 4; i++) O[c][i] *= al[i];
    asm volatile("" ::: "memory");  // keep ds_reads below the ds_writes above
    const short8 pf0 = *(const short8*)&Ps[w][lx][quad * 8];
    const short8 pf1 = *(const short8*)&Ps[w][lx][32 + quad * 8];
#pragma unroll
    for (int c = 0; c < 4; c++) {
      O[c] = MFMA16(pf0, vf[c],     O[c]);
      O[c] = MFMA16(pf1, vf[4 + c], O[c]);
    }
  }

  // deposit per-wave state
  if (lx == 0) {
#pragma unroll
    for (int i = 0; i < 4; i++) {
      mS[w][quad * 4 + i] = m_i[i];
      lS[w][quad * 4 + i] = l_i[i];
    }
  }
#pragma unroll
  for (int c = 0; c < 4; c++)
#pragma unroll
    for (int i = 0; i < 4; i++) Os[w][quad * 4 + i][16 * c + lx] = O[c][i];

  // wave 0: logits for global pairs above the diagonal
  if (w == 0) {
#pragma unroll
    for (int p = 0; p < 3; p++) {
      const int R = (p == 0) ? R0 : (p == 1) ? R1 : R2;
      const int C = (p == 0) ? C0 : (p == 1) ? C1 : C2;
      const int act = (R >= q0 && R < q0 + 16 && C > R);
      float d = 0.f;
      if (act) {
        const float qv = bf2f(QP[((size_t)b * SEQ + R) * 64 + l]);
        const float kv = bf2f(KP[((size_t)b * SEQ + C) * 64 + l]);
        d = qv * kv;
#pragma unroll
        for (int off = 32; off >= 1; off >>= 1) d += __shfl_xor(d, off);
        d *= 0.125f;
      }
      if (l == 0) { lgF[p] = act; lgS[p] = d; }
    }
  }
  __syncthreads();

  // merge the 4 wave states (+ pair fixups), normalize, store
  {
    const int row = tid >> 4;          // 0..15
    const int d0  = (tid & 15) * 4;    // 0..60
    const int Rs[3] = {R0, R1, R2};
    const int Cs3[3] = {C0, C1, C2};

    float mf = -INFINITY;
#pragma unroll
    for (int w4 = 0; w4 < 4; w4++) mf = fmaxf(mf, mS[w4][row]);
#pragma unroll
    for (int p = 0; p < 3; p++)
      if (lgF[p] && (Rs[p] - q0) == row) mf = fmaxf(mf, lgS[p]);

    float lf = 0.f;
    float o0 = 0.f, o1 = 0.f, o2 = 0.f, o3 = 0.f;
#pragma unroll
    for (int w4 = 0; w4 < 4; w4++) {
      const float a = __expf(mS[w4][row] - mf);
      lf += a * lS[w4][row];
      const float* op = &Os[w4][row][d0];
      o0 += a * op[0]; o1 += a * op[1]; o2 += a * op[2]; o3 += a * op[3];
    }
#pragma unroll
    for (int p = 0; p < 3; p++) {
      if (lgF[p] && (Rs[p] - q0) == row) {
        const float pe = __expf(lgS[p] - mf);
        lf += pe;
        const int C = Cs3[p];
        o0 += pe * bf2f(Vb[(size_t)(d0 + 0) * SEQ + C]);
        o1 += pe * bf2f(Vb[(size_t)(d0 + 1) * SEQ + C]);
        o2 += pe * bf2f(Vb[(size_t)(d0 + 2) * SEQ + C]);
        o3 += pe * bf2f(Vb[(size_t)(d0 + 3) * SEQ + C]);
      }
    }
    const float inv = 1.0f / lf;
    float4 r;
    r.x = o0 * inv; r.y = o1 * inv; r.z = o2 * inv; r.w = o3 * inv;
    *(float4*)(out + ((size_t)b * SEQ + q0 + row) * 64 + d0) = r;
  }
}

// ================================= launch =====================================
extern "C" void kernel_launch(void* const* d_in, const int* in_sizes, int n_in,
                              void* d_out, int out_size, void* d_ws,
                              size_t ws_size, hipStream_t stream) {
  const float* xq = (const float*)d_in[0];
  const float* xk = (const float*)d_in[1];
  const float* xv = (const float*)d_in[2];
  const float* Wq = (const float*)d_in[3];
  const float* bq = (const float*)d_in[4];
  const float* Wk = (const float*)d_in[5];
  const float* bk = (const float*)d_in[6];
  const float* Wv = (const float*)d_in[7];
  const float* bv = (const float*)d_in[8];
  float* out = (float*)d_out;

  // workspace (bf16): QP 1MB, KP 1MB, VPT 1MB, WT 384KB
  unsigned short* QP  = (unsigned short*)d_ws;
  unsigned short* KP  = QP + (size_t)NBATCH * SEQ * 64;
  unsigned short* VPT = KP + (size_t)NBATCH * SEQ * 64;
  unsigned short* WT  = VPT + (size_t)NBATCH * 64 * SEQ;

  nprng::PCG64 g;
  nprng::pcg_seed_from_seedseq0(g);
  long long rows[3], cols[3];
  nprng::choice3_2048(g, rows);
  nprng::choice3_2048(g, cols);

  wtrans_kernel<<<768, 256, 0, stream>>>(Wq, Wk, Wv, WT);

  dim3 pgrid(512, 3);
  proj_kernel<<<pgrid, 256, 0, stream>>>(xq, xk, xv, WT, bq, bk, bv, QP, KP, VPT);

  dim3 agrid(SEQ / 16, NBATCH);
  attn_kernel<<<agrid, 256, 0, stream>>>(
      QP, KP, VPT, out, (int)rows[0], (int)cols[0], (int)rows[1], (int)cols[1],
      (int)rows[2], (int)cols[2]);
}

// Round 4
// 175.588 us; speedup vs baseline: 2.2539x; 1.0732x over previous
//
#include <hip/hip_runtime.h>
#include <cstdint>
#include <cstddef>
#include <math.h>

#define SEQ    2048
#define NBATCH 4
#define DIN    1024
#define DH     64

typedef __attribute__((ext_vector_type(8))) short  short8;   // 8 x bf16 (4 VGPRs)
typedef __attribute__((ext_vector_type(4))) float  floatx4;  // MFMA C/D
typedef __attribute__((ext_vector_type(4))) unsigned short ushort4v;

#define MFMA16(a, b, c) __builtin_amdgcn_mfma_f32_16x16x32_bf16((a), (b), (c), 0, 0, 0)

__device__ __forceinline__ unsigned short f2bf(float x) {
  unsigned u = __float_as_uint(x);
  return (unsigned short)((u + 0x8000u) >> 16);   // round-half-up; values finite
}
__device__ __forceinline__ float bf2f(unsigned short h) {
  return __uint_as_float(((unsigned)h) << 16);
}

// ======================= host-side numpy RNG replication =======================
namespace nprng {

struct PCG64 {
  __uint128_t state, inc;
  bool has_uint32;
  uint32_t uinteger;
};

static inline void pcg_step(PCG64 &g) {
  const __uint128_t MULT =
      (((__uint128_t)0x2360ed051fc65da4ULL) << 64) | 0x4385df649fccf645ULL;
  g.state = g.state * MULT + g.inc;
}

static inline uint64_t pcg_output(const PCG64 &g) {
  uint64_t hi = (uint64_t)(g.state >> 64);
  uint64_t lo = (uint64_t)g.state;
  uint64_t x = hi ^ lo;
  unsigned rot = (unsigned)(g.state >> 122) & 63u;
  return (x >> rot) | (x << ((64u - rot) & 63u));
}

static inline uint64_t pcg_next64(PCG64 &g) { pcg_step(g); return pcg_output(g); }

static inline uint32_t pcg_next32(PCG64 &g) {
  if (g.has_uint32) { g.has_uint32 = false; return g.uinteger; }
  uint64_t n = pcg_next64(g);
  g.has_uint32 = true;
  g.uinteger = (uint32_t)(n >> 32);
  return (uint32_t)(n & 0xffffffffu);
}

static inline void pcg_seed_from_seedseq0(PCG64 &g) {
  const uint32_t MULT_A = 0x931e8875u;
  const uint32_t MULT_B = 0x58f38dedu;
  const uint32_t MIX_L  = 0xca01f9ddu;
  const uint32_t MIX_R  = 0x4973f715u;
  uint32_t hc = 0x43b0d7e5u;  // INIT_A
  uint32_t pool[4];
  for (int i = 0; i < 4; i++) {
    uint32_t v = 0u;
    v ^= hc; hc *= MULT_A; v *= hc; v ^= v >> 16;
    pool[i] = v;
  }
  for (int is = 0; is < 4; is++) {
    for (int id = 0; id < 4; id++) {
      if (is == id) continue;
      uint32_t h = pool[is];
      h ^= hc; hc *= MULT_A; h *= hc; h ^= h >> 16;
      uint32_t r = (pool[id] * MIX_L) ^ (h * MIX_R);
      r ^= r >> 16;
      pool[id] = r;
    }
  }
  uint32_t hb = 0x8b51f9ddu;  // INIT_B
  uint32_t w[8];
  for (int i = 0; i < 8; i++) {
    uint32_t v = pool[i & 3];
    v ^= hb; hb *= MULT_B; v *= hb; v ^= v >> 16;
    w[i] = v;
  }
  uint64_t sv[4];
  for (int k = 0; k < 4; k++)
    sv[k] = (uint64_t)w[2 * k] | ((uint64_t)w[2 * k + 1] << 32);
  __uint128_t initstate = (((__uint128_t)sv[0]) << 64) | sv[1];
  __uint128_t initseq   = (((__uint128_t)sv[2]) << 64) | sv[3];
  g.state = 0; g.inc = (initseq << 1) | 1;
  pcg_step(g);
  g.state += initstate;
  pcg_step(g);
  g.has_uint32 = false; g.uinteger = 0;
}

static inline uint32_t bounded32(PCG64 &g, uint32_t rng /*inclusive max*/) {
  if (rng == 0) return 0;
  const uint32_t rng_excl = rng + 1u;
  uint64_t m = (uint64_t)pcg_next32(g) * (uint64_t)rng_excl;
  uint32_t leftover = (uint32_t)m;
  if (leftover < rng_excl) {
    const uint32_t threshold = (uint32_t)(0xffffffffu - rng) % rng_excl;
    while (leftover < threshold) {
      m = (uint64_t)pcg_next32(g) * (uint64_t)rng_excl;
      leftover = (uint32_t)m;
    }
  }
  return (uint32_t)(m >> 32);
}

static inline void choice3_2048(PCG64 &g, long long idx[3]) {
  const int pop = 2048, sz = 3;
  uint64_t hs[4] = { (uint64_t)-1, (uint64_t)-1, (uint64_t)-1, (uint64_t)-1 };
  const uint64_t mask = 3;
  for (int j = pop - sz; j < pop; j++) {
    uint64_t val = (uint64_t)bounded32(g, (uint32_t)j);
    uint64_t loc = val & mask;
    while (hs[loc] != (uint64_t)-1 && hs[loc] != val) loc = (loc + 1) & mask;
    if (hs[loc] == (uint64_t)-1) {
      hs[loc] = val;
      idx[j - pop + sz] = (long long)val;
    } else {
      loc = (uint64_t)j & mask;
      while (hs[loc] != (uint64_t)-1) loc = (loc + 1) & mask;
      hs[loc] = (uint64_t)j;
      idx[j - pop + sz] = (long long)j;
    }
  }
  for (int i = 2; i >= 1; i--) {
    uint32_t j = bounded32(g, (uint32_t)i);
    long long t = idx[j]; idx[j] = idx[i]; idx[i] = t;
  }
}

}  // namespace nprng

// ==================== kernel 0: W -> W^T bf16 (tiny, once) ====================
// WT layout: [proj][n=64][k=1024] bf16.
__global__ __launch_bounds__(256) void wtrans_kernel(
    const float* __restrict__ Wq, const float* __restrict__ Wk,
    const float* __restrict__ Wv, unsigned short* __restrict__ WT) {
  int idx = blockIdx.x * 256 + threadIdx.x;     // 0 .. 3*64*1024-1
  int p   = idx >> 16;
  int rem = idx & 65535;
  int n   = rem >> 10;
  int k   = rem & 1023;
  const float* W = (p == 0) ? Wq : (p == 1) ? Wk : Wv;
  WT[idx] = f2bf(W[k * 64 + n]);
}

// ============ projections: coalesced LDS-staged bf16 MFMA GEMM ================
// grid (256, 3), 256 threads (4 waves). Block = 32 seq-rows, N=64, K=1024 in
// 4 chunks of 256. X staged via coalesced float4 loads (each wave-instruction
// covers one contiguous 1 KB row) -> bf16 in padded LDS. W fragments in regs
// (L2-resident). Next chunk's X/W prefetched into regs during compute.
// Wave w owns n-cols [16w,16w+16); 2 m-fragments (rows 0-15, 16-31).
__global__ __launch_bounds__(256, 3) void proj_kernel(
    const float* __restrict__ xq, const float* __restrict__ xk,
    const float* __restrict__ xv, const unsigned short* __restrict__ WT,
    const float* __restrict__ bq, const float* __restrict__ bk,
    const float* __restrict__ bv,
    unsigned short* __restrict__ QP, unsigned short* __restrict__ KP,
    unsigned short* __restrict__ VPT) {
  const int proj = blockIdx.y;
  const float* X    = (proj == 0) ? xq : (proj == 1) ? xk : xv;
  const float* bias = (proj == 0) ? bq : (proj == 1) ? bk : bv;

  const int m0   = blockIdx.x * 32;
  const int tid  = threadIdx.x;
  const int w    = tid >> 6;
  const int l    = tid & 63;
  const int quad = l >> 4;
  const int lx   = l & 15;

  __shared__ unsigned short Xs[32][264];   // bf16 X chunk, stride 264 (+8 pad)
  __shared__ float Cs[32][68];             // epilogue staging

  const float* Xg = X + (size_t)m0 * DIN;
  const unsigned short* Wrow = WT + (size_t)proj * 65536 + (size_t)(w * 16 + lx) * 1024 + quad * 8;

  // thread's staging rows: r_i = 4*i + w  (i=0..7); col = l (float4 granules)
  float4 xg[8];
  short8 wc[8], wn[8];

#pragma unroll
  for (int i = 0; i < 8; i++)
    xg[i] = *(const float4*)(Xg + (size_t)(4 * i + w) * DIN + l * 4);
#pragma unroll
  for (int ks = 0; ks < 8; ks++)
    wc[ks] = *(const short8*)(Wrow + ks * 32);

  floatx4 acc0 = {0.f, 0.f, 0.f, 0.f}, acc1 = acc0;

#pragma unroll
  for (int c = 0; c < 4; c++) {
    // convert staged regs -> bf16 LDS (ds_write_b64 per row-chunk)
#pragma unroll
    for (int i = 0; i < 8; i++) {
      ushort4v v;
      v[0] = f2bf(xg[i].x); v[1] = f2bf(xg[i].y);
      v[2] = f2bf(xg[i].z); v[3] = f2bf(xg[i].w);
      *(ushort4v*)&Xs[4 * i + w][l * 4] = v;
    }
    // prefetch next chunk into regs (flies during compute)
    if (c < 3) {
      const int k0n = (c + 1) * 256;
#pragma unroll
      for (int i = 0; i < 8; i++)
        xg[i] = *(const float4*)(Xg + (size_t)(4 * i + w) * DIN + k0n + l * 4);
#pragma unroll
      for (int ks = 0; ks < 8; ks++)
        wn[ks] = *(const short8*)(Wrow + k0n + ks * 32);
    }
    __syncthreads();

#pragma unroll
    for (int ks = 0; ks < 8; ks++) {
      const short8 a0 = *(const short8*)&Xs[lx][ks * 32 + quad * 8];
      const short8 a1 = *(const short8*)&Xs[16 + lx][ks * 32 + quad * 8];
      acc0 = MFMA16(a0, wc[ks], acc0);
      acc1 = MFMA16(a1, wc[ks], acc1);
    }
    __syncthreads();

    if (c < 3) {
#pragma unroll
      for (int ks = 0; ks < 8; ks++) wc[ks] = wn[ks];
    }
  }

  // epilogue: acc(+bias) -> Cs -> coalesced bf16 stores
  const float bb = bias[w * 16 + lx];
#pragma unroll
  for (int i = 0; i < 4; i++) {
    Cs[quad * 4 + i][w * 16 + lx]      = acc0[i] + bb;
    Cs[16 + quad * 4 + i][w * 16 + lx] = acc1[i] + bb;
  }
  __syncthreads();

  if (proj < 2) {
    unsigned short* outp = (proj == 0) ? QP : KP;
    const int row = tid >> 3;            // 0..31
    const int d0  = (tid & 7) * 8;       // 0..56
    short8 v;
#pragma unroll
    for (int j = 0; j < 8; j++) v[j] = (short)f2bf(Cs[row][d0 + j]);
    *(short8*)(outp + (size_t)(m0 + row) * 64 + d0) = v;
  } else {
    // V transposed: VPT[b*64 + dim][2048]
    const int dim = tid >> 2;            // 0..63
    const int s0  = (tid & 3) * 8;       // 0,8,16,24
    const int bq_ = m0 >> 11;            // batch
    const int sq  = (m0 & 2047) + s0;
    short8 v;
#pragma unroll
    for (int j = 0; j < 8; j++) v[j] = (short)f2bf(Cs[s0 + j][dim]);
    *(short8*)(VPT + ((size_t)bq_ * 64 + dim) * SEQ + sq) = v;
  }
}

// ===================== flash attention: bf16 MFMA, 1 barrier ==================
// grid (128, 4), 256 threads (4 waves). Block = 16 q-rows; wave w processes
// key-tiles t = w, w+4, ... with independent online-softmax state; merged once.
// Single-buffered fragments (spill-safe). q-tiles pair-complemented so
// co-resident blocks have ~equal causal work.
__global__ __launch_bounds__(256, 2) void attn_kernel(
    const unsigned short* __restrict__ QP, const unsigned short* __restrict__ KP,
    const unsigned short* __restrict__ VPT, float* __restrict__ out,
    int R0, int C0, int R1, int C1, int R2, int C2) {
  const int b    = blockIdx.y;
  const int bx   = blockIdx.x;
  const int qi   = (bx & 1) ? (127 - (bx >> 1)) : (bx >> 1);  // heavy/light pairing
  const int q0   = qi * 16;
  const int tid  = threadIdx.x;
  const int w    = tid >> 6;
  const int l    = tid & 63;
  const int quad = l >> 4;
  const int lx   = l & 15;

  __shared__ unsigned short Ps[4][16][72];
  __shared__ float Os[4][16][64];
  __shared__ float mS[4][16], lS[4][16];
  __shared__ float lgS[3];
  __shared__ int   lgF[3];

  const unsigned short* Qb = QP + ((size_t)b * SEQ + q0) * 64;
  const unsigned short* Kb = KP + (size_t)b * SEQ * 64;
  const unsigned short* Vb = VPT + (size_t)b * 64 * SEQ;

  const short8 aq0 = *(const short8*)(Qb + (size_t)lx * 64 + quad * 8);
  const short8 aq1 = *(const short8*)(Qb + (size_t)lx * 64 + 32 + quad * 8);

  floatx4 O[4];
  float m_i[4], l_i[4];
#pragma unroll
  for (int c = 0; c < 4; c++) O[c] = (floatx4){0.f, 0.f, 0.f, 0.f};
#pragma unroll
  for (int i = 0; i < 4; i++) { m_i[i] = -INFINITY; l_i[i] = 0.f; }

  const int T = (q0 + 79) >> 6;   // key-tiles needed (64 keys each)

  for (int t = w; t < T; t += 4) {
    const int k0 = t << 6;
    const bool mT = (t == T - 1);

    short8 kf[8], vf[8];
#pragma unroll
    for (int c = 0; c < 4; c++) {
#pragma unroll
      for (int s = 0; s < 2; s++) {
        kf[c * 2 + s] = *(const short8*)(Kb + (size_t)(k0 + 16 * c + lx) * 64 + s * 32 + quad * 8);
        vf[s * 4 + c] = *(const short8*)(Vb + (size_t)(16 * c + lx) * SEQ + k0 + s * 32 + quad * 8);
      }
    }

    floatx4 sc[4];
#pragma unroll
    for (int c = 0; c < 4; c++) {
      sc[c] = (floatx4){0.f, 0.f, 0.f, 0.f};
      sc[c] = MFMA16(aq0, kf[2 * c], sc[c]);
      sc[c] = MFMA16(aq1, kf[2 * c + 1], sc[c]);
    }

    float mt[4], al[4];
#pragma unroll
    for (int i = 0; i < 4; i++) {
      const int rowg = q0 + quad * 4 + i;
      float vmax = -INFINITY;
#pragma unroll
      for (int c = 0; c < 4; c++) {
        float v = sc[c][i] * 0.125f;
        if (mT && (k0 + 16 * c + lx) > rowg) v = -INFINITY;
        sc[c][i] = v;
        vmax = fmaxf(vmax, v);
      }
      mt[i] = vmax;
    }
#pragma unroll
    for (int i = 0; i < 4; i++) {
#pragma unroll
      for (int off = 8; off >= 1; off >>= 1)
        mt[i] = fmaxf(mt[i], __shfl_xor(mt[i], off));
      const float mn = fmaxf(m_i[i], mt[i]);
      al[i] = __expf(m_i[i] - mn);
      m_i[i] = mn;
      float s = 0.f;
#pragma unroll
      for (int c = 0; c < 4; c++) {
        float p = __expf(sc[c][i] - mn);
        Ps[w][quad * 4 + i][16 * c + lx] = f2bf(p);
        s += p;
      }
#pragma unroll
      for (int off = 8; off >= 1; off >>= 1) s += __shfl_xor(s, off);
      l_i[i] = l_i[i] * al[i] + s;
    }
#pragma unroll
    for (int c = 0; c < 4; c++)
#pragma unroll
      for (int i = 0; i < 4; i++) O[c][i] *= al[i];
    asm volatile("" ::: "memory");  // keep ds_reads below the ds_writes above
    const short8 pf0 = *(const short8*)&Ps[w][lx][quad * 8];
    const short8 pf1 = *(const short8*)&Ps[w][lx][32 + quad * 8];
#pragma unroll
    for (int c = 0; c < 4; c++) {
      O[c] = MFMA16(pf0, vf[c],     O[c]);
      O[c] = MFMA16(pf1, vf[4 + c], O[c]);
    }
  }

  // deposit per-wave state
  if (lx == 0) {
#pragma unroll
    for (int i = 0; i < 4; i++) {
      mS[w][quad * 4 + i] = m_i[i];
      lS[w][quad * 4 + i] = l_i[i];
    }
  }
#pragma unroll
  for (int c = 0; c < 4; c++)
#pragma unroll
    for (int i = 0; i < 4; i++) Os[w][quad * 4 + i][16 * c + lx] = O[c][i];

  // wave 0: logits for global pairs above the diagonal
  if (w == 0) {
#pragma unroll
    for (int p = 0; p < 3; p++) {
      const int R = (p == 0) ? R0 : (p == 1) ? R1 : R2;
      const int C = (p == 0) ? C0 : (p == 1) ? C1 : C2;
      const int act = (R >= q0 && R < q0 + 16 && C > R);
      float d = 0.f;
      if (act) {
        const float qv = bf2f(QP[((size_t)b * SEQ + R) * 64 + l]);
        const float kv = bf2f(KP[((size_t)b * SEQ + C) * 64 + l]);
        d = qv * kv;
#pragma unroll
        for (int off = 32; off >= 1; off >>= 1) d += __shfl_xor(d, off);
        d *= 0.125f;
      }
      if (l == 0) { lgF[p] = act; lgS[p] = d; }
    }
  }
  __syncthreads();

  // merge the 4 wave states (+ pair fixups), normalize, store
  {
    const int row = tid >> 4;          // 0..15
    const int d0  = (tid & 15) * 4;    // 0..60
    const int Rs[3] = {R0, R1, R2};
    const int Cs3[3] = {C0, C1, C2};

    float mf = -INFINITY;
#pragma unroll
    for (int w4 = 0; w4 < 4; w4++) mf = fmaxf(mf, mS[w4][row]);
#pragma unroll
    for (int p = 0; p < 3; p++)
      if (lgF[p] && (Rs[p] - q0) == row) mf = fmaxf(mf, lgS[p]);

    float lf = 0.f;
    float o0 = 0.f, o1 = 0.f, o2 = 0.f, o3 = 0.f;
#pragma unroll
    for (int w4 = 0; w4 < 4; w4++) {
      const float a = __expf(mS[w4][row] - mf);
      lf += a * lS[w4][row];
      const float* op = &Os[w4][row][d0];
      o0 += a * op[0]; o1 += a * op[1]; o2 += a * op[2]; o3 += a * op[3];
    }
#pragma unroll
    for (int p = 0; p < 3; p++) {
      if (lgF[p] && (Rs[p] - q0) == row) {
        const float pe = __expf(lgS[p] - mf);
        lf += pe;
        const int C = Cs3[p];
        o0 += pe * bf2f(Vb[(size_t)(d0 + 0) * SEQ + C]);
        o1 += pe * bf2f(Vb[(size_t)(d0 + 1) * SEQ + C]);
        o2 += pe * bf2f(Vb[(size_t)(d0 + 2) * SEQ + C]);
        o3 += pe * bf2f(Vb[(size_t)(d0 + 3) * SEQ + C]);
      }
    }
    const float inv = 1.0f / lf;
    float4 r;
    r.x = o0 * inv; r.y = o1 * inv; r.z = o2 * inv; r.w = o3 * inv;
    *(float4*)(out + ((size_t)b * SEQ + q0 + row) * 64 + d0) = r;
  }
}

// ================================= launch =====================================
extern "C" void kernel_launch(void* const* d_in, const int* in_sizes, int n_in,
                              void* d_out, int out_size, void* d_ws,
                              size_t ws_size, hipStream_t stream) {
  const float* xq = (const float*)d_in[0];
  const float* xk = (const float*)d_in[1];
  const float* xv = (const float*)d_in[2];
  const float* Wq = (const float*)d_in[3];
  const float* bq = (const float*)d_in[4];
  const float* Wk = (const float*)d_in[5];
  const float* bk = (const float*)d_in[6];
  const float* Wv = (const float*)d_in[7];
  const float* bv = (const float*)d_in[8];
  float* out = (float*)d_out;

  // workspace (bf16): QP 1MB, KP 1MB, VPT 1MB, WT 384KB
  unsigned short* QP  = (unsigned short*)d_ws;
  unsigned short* KP  = QP + (size_t)NBATCH * SEQ * 64;
  unsigned short* VPT = KP + (size_t)NBATCH * SEQ * 64;
  unsigned short* WT  = VPT + (size_t)NBATCH * 64 * SEQ;

  nprng::PCG64 g;
  nprng::pcg_seed_from_seedseq0(g);
  long long rows[3], cols[3];
  nprng::choice3_2048(g, rows);
  nprng::choice3_2048(g, cols);

  wtrans_kernel<<<768, 256, 0, stream>>>(Wq, Wk, Wv, WT);

  dim3 pgrid(256, 3);
  proj_kernel<<<pgrid, 256, 0, stream>>>(xq, xk, xv, WT, bq, bk, bv, QP, KP, VPT);

  dim3 agrid(SEQ / 16, NBATCH);
  attn_kernel<<<agrid, 256, 0, stream>>>(
      QP, KP, VPT, out, (int)rows[0], (int)cols[0], (int)rows[1], (int)cols[1],
      (int)rows[2], (int)cols[2]);
}

// Round 5
// 168.650 us; speedup vs baseline: 2.3467x; 1.0411x over previous
//
#include <hip/hip_runtime.h>
#include <cstdint>
#include <cstddef>
#include <math.h>

#define SEQ    2048
#define NBATCH 4
#define DIN    1024
#define DH     64

typedef __attribute__((ext_vector_type(8))) short  short8;   // 8 x bf16 (4 VGPRs)
typedef __attribute__((ext_vector_type(4))) float  floatx4;  // MFMA C/D
typedef __attribute__((ext_vector_type(4))) unsigned short ushort4v;

#define MFMA16(a, b, c) __builtin_amdgcn_mfma_f32_16x16x32_bf16((a), (b), (c), 0, 0, 0)

__device__ __forceinline__ unsigned short f2bf(float x) {
  unsigned u = __float_as_uint(x);
  return (unsigned short)((u + 0x8000u) >> 16);   // round-half-up; values finite
}
__device__ __forceinline__ float bf2f(unsigned short h) {
  return __uint_as_float(((unsigned)h) << 16);
}

// async global->LDS DMA: no dest VGPR, scheduler cannot sink it.
// gptr is PER-LANE (base + lane*size); lds dest is wave-uniform base,
// HW deposits at base + lane*size.
__device__ __forceinline__ void async_cp4(const void* g, void* l) {
  __builtin_amdgcn_global_load_lds(
      (const __attribute__((address_space(1))) void*)g,
      (__attribute__((address_space(3))) void*)l, 4, 0, 0);
}
__device__ __forceinline__ void async_cp16(const void* g, void* l) {
  __builtin_amdgcn_global_load_lds(
      (const __attribute__((address_space(1))) void*)g,
      (__attribute__((address_space(3))) void*)l, 16, 0, 0);
}

// ======================= host-side numpy RNG replication =======================
namespace nprng {

struct PCG64 {
  __uint128_t state, inc;
  bool has_uint32;
  uint32_t uinteger;
};

static inline void pcg_step(PCG64 &g) {
  const __uint128_t MULT =
      (((__uint128_t)0x2360ed051fc65da4ULL) << 64) | 0x4385df649fccf645ULL;
  g.state = g.state * MULT + g.inc;
}

static inline uint64_t pcg_output(const PCG64 &g) {
  uint64_t hi = (uint64_t)(g.state >> 64);
  uint64_t lo = (uint64_t)g.state;
  uint64_t x = hi ^ lo;
  unsigned rot = (unsigned)(g.state >> 122) & 63u;
  return (x >> rot) | (x << ((64u - rot) & 63u));
}

static inline uint64_t pcg_next64(PCG64 &g) { pcg_step(g); return pcg_output(g); }

static inline uint32_t pcg_next32(PCG64 &g) {
  if (g.has_uint32) { g.has_uint32 = false; return g.uinteger; }
  uint64_t n = pcg_next64(g);
  g.has_uint32 = true;
  g.uinteger = (uint32_t)(n >> 32);
  return (uint32_t)(n & 0xffffffffu);
}

static inline void pcg_seed_from_seedseq0(PCG64 &g) {
  const uint32_t MULT_A = 0x931e8875u;
  const uint32_t MULT_B = 0x58f38dedu;
  const uint32_t MIX_L  = 0xca01f9ddu;
  const uint32_t MIX_R  = 0x4973f715u;
  uint32_t hc = 0x43b0d7e5u;  // INIT_A
  uint32_t pool[4];
  for (int i = 0; i < 4; i++) {
    uint32_t v = 0u;
    v ^= hc; hc *= MULT_A; v *= hc; v ^= v >> 16;
    pool[i] = v;
  }
  for (int is = 0; is < 4; is++) {
    for (int id = 0; id < 4; id++) {
      if (is == id) continue;
      uint32_t h = pool[is];
      h ^= hc; hc *= MULT_A; h *= hc; h ^= h >> 16;
      uint32_t r = (pool[id] * MIX_L) ^ (h * MIX_R);
      r ^= r >> 16;
      pool[id] = r;
    }
  }
  uint32_t hb = 0x8b51f9ddu;  // INIT_B
  uint32_t w[8];
  for (int i = 0; i < 8; i++) {
    uint32_t v = pool[i & 3];
    v ^= hb; hb *= MULT_B; v *= hb; v ^= v >> 16;
    w[i] = v;
  }
  uint64_t sv[4];
  for (int k = 0; k < 4; k++)
    sv[k] = (uint64_t)w[2 * k] | ((uint64_t)w[2 * k + 1] << 32);
  __uint128_t initstate = (((__uint128_t)sv[0]) << 64) | sv[1];
  __uint128_t initseq   = (((__uint128_t)sv[2]) << 64) | sv[3];
  g.state = 0; g.inc = (initseq << 1) | 1;
  pcg_step(g);
  g.state += initstate;
  pcg_step(g);
  g.has_uint32 = false; g.uinteger = 0;
}

static inline uint32_t bounded32(PCG64 &g, uint32_t rng /*inclusive max*/) {
  if (rng == 0) return 0;
  const uint32_t rng_excl = rng + 1u;
  uint64_t m = (uint64_t)pcg_next32(g) * (uint64_t)rng_excl;
  uint32_t leftover = (uint32_t)m;
  if (leftover < rng_excl) {
    const uint32_t threshold = (uint32_t)(0xffffffffu - rng) % rng_excl;
    while (leftover < threshold) {
      m = (uint64_t)pcg_next32(g) * (uint64_t)rng_excl;
      leftover = (uint32_t)m;
    }
  }
  return (uint32_t)(m >> 32);
}

static inline void choice3_2048(PCG64 &g, long long idx[3]) {
  const int pop = 2048, sz = 3;
  uint64_t hs[4] = { (uint64_t)-1, (uint64_t)-1, (uint64_t)-1, (uint64_t)-1 };
  const uint64_t mask = 3;
  for (int j = pop - sz; j < pop; j++) {
    uint64_t val = (uint64_t)bounded32(g, (uint32_t)j);
    uint64_t loc = val & mask;
    while (hs[loc] != (uint64_t)-1 && hs[loc] != val) loc = (loc + 1) & mask;
    if (hs[loc] == (uint64_t)-1) {
      hs[loc] = val;
      idx[j - pop + sz] = (long long)val;
    } else {
      loc = (uint64_t)j & mask;
      while (hs[loc] != (uint64_t)-1) loc = (loc + 1) & mask;
      hs[loc] = (uint64_t)j;
      idx[j - pop + sz] = (long long)j;
    }
  }
  for (int i = 2; i >= 1; i--) {
    uint32_t j = bounded32(g, (uint32_t)i);
    long long t = idx[j]; idx[j] = idx[i]; idx[i] = t;
  }
}

}  // namespace nprng

// ==================== kernel 0: W -> chunked W^T bf16 (tiny) ==================
// WTc layout: [proj][kc=k/128][col(64)][kk=k%128] bf16 — each (proj,kc) chunk is
// a contiguous 16 KB block so proj can DMA it with size-16 global_load_lds.
__global__ __launch_bounds__(256) void wtrans_kernel(
    const float* __restrict__ Wq, const float* __restrict__ Wk,
    const float* __restrict__ Wv, unsigned short* __restrict__ WTc) {
  int idx = blockIdx.x * 256 + threadIdx.x;     // 0 .. 3*64*1024-1
  int p   = idx >> 16;
  int rem = idx & 65535;
  int n   = rem >> 10;
  int k   = rem & 1023;
  const float* W = (p == 0) ? Wq : (p == 1) ? Wk : Wv;
  unsigned short v = f2bf(W[k * 64 + n]);
  int dst = ((p * 8 + (k >> 7)) * 64 + n) * 128 + (k & 127);
  WTc[dst] = v;
}

// ======== projections: global_load_lds-staged bf16 MFMA GEMM (m97-style) ======
// grid 768 x 256 thr (4 waves). Block = 32 rows of the concatenated 24576-row
// [q;k;v] input, N=64, K=1024 in 8 chunks of 128. X staged fp32 via async DMA
// (row stride 132 floats -> 4-bank rotation, 2-way conflicts = free); W chunk
// staged via size-16 DMA (1040 B group stride). fp32->bf16 on the LDS-read
// side. 2x2 wave split: wave w = rows (w&1)*16.., cols (w>>1)*32..
__global__ __launch_bounds__(256, 3) void proj_kernel(
    const float* __restrict__ xq, const float* __restrict__ xk,
    const float* __restrict__ xv, const unsigned short* __restrict__ WTc,
    const float* __restrict__ bq, const float* __restrict__ bk,
    const float* __restrict__ bv,
    unsigned short* __restrict__ QP, unsigned short* __restrict__ KP,
    unsigned short* __restrict__ VPT) {
  const int m0g  = blockIdx.x * 32;        // 0..24544
  const int proj = m0g >> 13;              // 0,1,2
  const int m0   = m0g & 8191;             // row within proj
  const float* X    = (proj == 0) ? xq : (proj == 1) ? xk : xv;
  const float* bias = (proj == 0) ? bq : (proj == 1) ? bk : bv;

  const int tid  = threadIdx.x;
  const int w    = tid >> 6;
  const int l    = tid & 63;
  const int quad = l >> 4;
  const int lx   = l & 15;
  const int mr   = (w & 1) * 16;           // wave's row half
  const int nc   = (w >> 1) * 32;          // wave's col half

  __shared__ float          Xs[32 * 132];  // fp32 X chunk, row stride 132
  __shared__ unsigned short Ws[16 * 520];  // bf16 W chunk, group(4 col) stride 520
  __shared__ float          Cs[32][68];    // epilogue staging

  const float* Xblk = X + (size_t)m0 * DIN;
  const unsigned short* Wpj = WTc + (size_t)proj * 8 * 8192;

  floatx4 acc0 = {0.f, 0.f, 0.f, 0.f}, acc1 = acc0;

  for (int kc = 0; kc < 8; kc++) {
    // ---- stage X: wave w DMAs rows 8w..8w+7 (2 half-row instrs each) ----
#pragma unroll
    for (int i = 0; i < 8; i++) {
      const int r = 8 * w + i;
      const float* g = Xblk + (size_t)r * DIN + kc * 128;
      async_cp4(g + l,      &Xs[r * 132]);        // floats 0..63
      async_cp4(g + 64 + l, &Xs[r * 132 + 64]);   // floats 64..127
    }
    // ---- stage W: wave w DMAs groups 4w..4w+3 (4 cols = 1024 B each) ----
#pragma unroll
    for (int i = 0; i < 4; i++) {
      const int g4 = 4 * w + i;
      const unsigned short* gsrc = Wpj + (size_t)kc * 8192 + g4 * 512;
      async_cp16((const char*)gsrc + l * 16, &Ws[g4 * 520]);
    }
    __syncthreads();   // drains vmcnt (incl. LDS-DMA) before reads

#pragma unroll
    for (int ks = 0; ks < 4; ks++) {
      const float* ap = &Xs[(mr + lx) * 132 + ks * 32 + quad * 8];
      const float4 f0 = *(const float4*)ap;
      const float4 f1 = *(const float4*)(ap + 4);
      short8 a;
      a[0] = f2bf(f0.x); a[1] = f2bf(f0.y); a[2] = f2bf(f0.z); a[3] = f2bf(f0.w);
      a[4] = f2bf(f1.x); a[5] = f2bf(f1.y); a[6] = f2bf(f1.z); a[7] = f2bf(f1.w);
      const int c0 = nc + lx, c1 = nc + 16 + lx;
      const short8 b0 = *(const short8*)&Ws[(c0 >> 2) * 520 + (c0 & 3) * 128 + ks * 32 + quad * 8];
      const short8 b1 = *(const short8*)&Ws[(c1 >> 2) * 520 + (c1 & 3) * 128 + ks * 32 + quad * 8];
      acc0 = MFMA16(a, b0, acc0);
      acc1 = MFMA16(a, b1, acc1);
    }
    __syncthreads();   // protect LDS from next chunk's DMA
  }

  // epilogue: acc(+bias) -> Cs -> coalesced bf16 stores
  const float bb0 = bias[nc + lx], bb1 = bias[nc + 16 + lx];
#pragma unroll
  for (int i = 0; i < 4; i++) {
    Cs[mr + quad * 4 + i][nc + lx]      = acc0[i] + bb0;
    Cs[mr + quad * 4 + i][nc + 16 + lx] = acc1[i] + bb1;
  }
  __syncthreads();

  if (proj < 2) {
    unsigned short* outp = (proj == 0) ? QP : KP;
    const int row = tid >> 3;            // 0..31
    const int d0  = (tid & 7) * 8;       // 0..56
    short8 v;
#pragma unroll
    for (int j = 0; j < 8; j++) v[j] = (short)f2bf(Cs[row][d0 + j]);
    *(short8*)(outp + (size_t)(m0 + row) * 64 + d0) = v;
  } else {
    // V transposed: VPT[b*64 + dim][2048]
    const int dim = tid >> 2;            // 0..63
    const int s0  = (tid & 3) * 8;       // 0,8,16,24
    const int bq_ = m0 >> 11;            // batch
    const int sq  = (m0 & 2047) + s0;
    short8 v;
#pragma unroll
    for (int j = 0; j < 8; j++) v[j] = (short)f2bf(Cs[s0 + j][dim]);
    *(short8*)(VPT + ((size_t)bq_ * 64 + dim) * SEQ + sq) = v;
  }
}

// ===================== flash attention: bf16 MFMA, 1 barrier ==================
// grid (128, 4), 256 threads (4 waves). Block = 16 q-rows; wave w processes
// key-tiles t = w, w+4, ... with independent online-softmax state; merged once.
// Single-buffered fragments (spill-safe). q-tiles pair-complemented so
// co-resident blocks have ~equal causal work.
__global__ __launch_bounds__(256, 2) void attn_kernel(
    const unsigned short* __restrict__ QP, const unsigned short* __restrict__ KP,
    const unsigned short* __restrict__ VPT, float* __restrict__ out,
    int R0, int C0, int R1, int C1, int R2, int C2) {
  const int b    = blockIdx.y;
  const int bx   = blockIdx.x;
  const int qi   = (bx & 1) ? (127 - (bx >> 1)) : (bx >> 1);  // heavy/light pairing
  const int q0   = qi * 16;
  const int tid  = threadIdx.x;
  const int w    = tid >> 6;
  const int l    = tid & 63;
  const int quad = l >> 4;
  const int lx   = l & 15;

  __shared__ unsigned short Ps[4][16][72];
  __shared__ float Os[4][16][64];
  __shared__ float mS[4][16], lS[4][16];
  __shared__ float lgS[3];
  __shared__ int   lgF[3];

  const unsigned short* Qb = QP + ((size_t)b * SEQ + q0) * 64;
  const unsigned short* Kb = KP + (size_t)b * SEQ * 64;
  const unsigned short* Vb = VPT + (size_t)b * 64 * SEQ;

  const short8 aq0 = *(const short8*)(Qb + (size_t)lx * 64 + quad * 8);
  const short8 aq1 = *(const short8*)(Qb + (size_t)lx * 64 + 32 + quad * 8);

  floatx4 O[4];
  float m_i[4], l_i[4];
#pragma unroll
  for (int c = 0; c < 4; c++) O[c] = (floatx4){0.f, 0.f, 0.f, 0.f};
#pragma unroll
  for (int i = 0; i < 4; i++) { m_i[i] = -INFINITY; l_i[i] = 0.f; }

  const int T = (q0 + 79) >> 6;   // key-tiles needed (64 keys each)

  for (int t = w; t < T; t += 4) {
    const int k0 = t << 6;
    const bool mT = (t == T - 1);

    short8 kf[8], vf[8];
#pragma unroll
    for (int c = 0; c < 4; c++) {
#pragma unroll
      for (int s = 0; s < 2; s++) {
        kf[c * 2 + s] = *(const short8*)(Kb + (size_t)(k0 + 16 * c + lx) * 64 + s * 32 + quad * 8);
        vf[s * 4 + c] = *(const short8*)(Vb + (size_t)(16 * c + lx) * SEQ + k0 + s * 32 + quad * 8);
      }
    }

    floatx4 sc[4];
#pragma unroll
    for (int c = 0; c < 4; c++) {
      sc[c] = (floatx4){0.f, 0.f, 0.f, 0.f};
      sc[c] = MFMA16(aq0, kf[2 * c], sc[c]);
      sc[c] = MFMA16(aq1, kf[2 * c + 1], sc[c]);
    }

    float mt[4], al[4];
#pragma unroll
    for (int i = 0; i < 4; i++) {
      const int rowg = q0 + quad * 4 + i;
      float vmax = -INFINITY;
#pragma unroll
      for (int c = 0; c < 4; c++) {
        float v = sc[c][i] * 0.125f;
        if (mT && (k0 + 16 * c + lx) > rowg) v = -INFINITY;
        sc[c][i] = v;
        vmax = fmaxf(vmax, v);
      }
      mt[i] = vmax;
    }
#pragma unroll
    for (int i = 0; i < 4; i++) {
#pragma unroll
      for (int off = 8; off >= 1; off >>= 1)
        mt[i] = fmaxf(mt[i], __shfl_xor(mt[i], off));
      const float mn = fmaxf(m_i[i], mt[i]);
      al[i] = __expf(m_i[i] - mn);
      m_i[i] = mn;
      float s = 0.f;
#pragma unroll
      for (int c = 0; c < 4; c++) {
        float p = __expf(sc[c][i] - mn);
        Ps[w][quad * 4 + i][16 * c + lx] = f2bf(p);
        s += p;
      }
#pragma unroll
      for (int off = 8; off >= 1; off >>= 1) s += __shfl_xor(s, off);
      l_i[i] = l_i[i] * al[i] + s;
    }
#pragma unroll
    for (int c = 0; c < 4; c++)
#pragma unroll
      for (int i = 0; i < 4; i++) O[c][i] *= al[i];
    asm volatile("" ::: "memory");  // keep ds_reads below the ds_writes above
    const short8 pf0 = *(const short8*)&Ps[w][lx][quad * 8];
    const short8 pf1 = *(const short8*)&Ps[w][lx][32 + quad * 8];
#pragma unroll
    for (int c = 0; c < 4; c++) {
      O[c] = MFMA16(pf0, vf[c],     O[c]);
      O[c] = MFMA16(pf1, vf[4 + c], O[c]);
    }
  }

  // deposit per-wave state
  if (lx == 0) {
#pragma unroll
    for (int i = 0; i < 4; i++) {
      mS[w][quad * 4 + i] = m_i[i];
      lS[w][quad * 4 + i] = l_i[i];
    }
  }
#pragma unroll
  for (int c = 0; c < 4; c++)
#pragma unroll
    for (int i = 0; i < 4; i++) Os[w][quad * 4 + i][16 * c + lx] = O[c][i];

  // wave 0: logits for global pairs above the diagonal
  if (w == 0) {
#pragma unroll
    for (int p = 0; p < 3; p++) {
      const int R = (p == 0) ? R0 : (p == 1) ? R1 : R2;
      const int C = (p == 0) ? C0 : (p == 1) ? C1 : C2;
      const int act = (R >= q0 && R < q0 + 16 && C > R);
      float d = 0.f;
      if (act) {
        const float qv = bf2f(QP[((size_t)b * SEQ + R) * 64 + l]);
        const float kv = bf2f(KP[((size_t)b * SEQ + C) * 64 + l]);
        d = qv * kv;
#pragma unroll
        for (int off = 32; off >= 1; off >>= 1) d += __shfl_xor(d, off);
        d *= 0.125f;
      }
      if (l == 0) { lgF[p] = act; lgS[p] = d; }
    }
  }
  __syncthreads();

  // merge the 4 wave states (+ pair fixups), normalize, store
  {
    const int row = tid >> 4;          // 0..15
    const int d0  = (tid & 15) * 4;    // 0..60
    const int Rs[3] = {R0, R1, R2};
    const int Cs3[3] = {C0, C1, C2};

    float mf = -INFINITY;
#pragma unroll
    for (int w4 = 0; w4 < 4; w4++) mf = fmaxf(mf, mS[w4][row]);
#pragma unroll
    for (int p = 0; p < 3; p++)
      if (lgF[p] && (Rs[p] - q0) == row) mf = fmaxf(mf, lgS[p]);

    float lf = 0.f;
    float o0 = 0.f, o1 = 0.f, o2 = 0.f, o3 = 0.f;
#pragma unroll
    for (int w4 = 0; w4 < 4; w4++) {
      const float a = __expf(mS[w4][row] - mf);
      lf += a * lS[w4][row];
      const float* op = &Os[w4][row][d0];
      o0 += a * op[0]; o1 += a * op[1]; o2 += a * op[2]; o3 += a * op[3];
    }
#pragma unroll
    for (int p = 0; p < 3; p++) {
      if (lgF[p] && (Rs[p] - q0) == row) {
        const float pe = __expf(lgS[p] - mf);
        lf += pe;
        const int C = Cs3[p];
        o0 += pe * bf2f(Vb[(size_t)(d0 + 0) * SEQ + C]);
        o1 += pe * bf2f(Vb[(size_t)(d0 + 1) * SEQ + C]);
        o2 += pe * bf2f(Vb[(size_t)(d0 + 2) * SEQ + C]);
        o3 += pe * bf2f(Vb[(size_t)(d0 + 3) * SEQ + C]);
      }
    }
    const float inv = 1.0f / lf;
    float4 r;
    r.x = o0 * inv; r.y = o1 * inv; r.z = o2 * inv; r.w = o3 * inv;
    *(float4*)(out + ((size_t)b * SEQ + q0 + row) * 64 + d0) = r;
  }
}

// ================================= launch =====================================
extern "C" void kernel_launch(void* const* d_in, const int* in_sizes, int n_in,
                              void* d_out, int out_size, void* d_ws,
                              size_t ws_size, hipStream_t stream) {
  const float* xq = (const float*)d_in[0];
  const float* xk = (const float*)d_in[1];
  const float* xv = (const float*)d_in[2];
  const float* Wq = (const float*)d_in[3];
  const float* bq = (const float*)d_in[4];
  const float* Wk = (const float*)d_in[5];
  const float* bk = (const float*)d_in[6];
  const float* Wv = (const float*)d_in[7];
  const float* bv = (const float*)d_in[8];
  float* out = (float*)d_out;

  // workspace (bf16): QP 1MB, KP 1MB, VPT 1MB, WTc 384KB
  unsigned short* QP  = (unsigned short*)d_ws;
  unsigned short* KP  = QP + (size_t)NBATCH * SEQ * 64;
  unsigned short* VPT = KP + (size_t)NBATCH * SEQ * 64;
  unsigned short* WTc = VPT + (size_t)NBATCH * 64 * SEQ;

  nprng::PCG64 g;
  nprng::pcg_seed_from_seedseq0(g);
  long long rows[3], cols[3];
  nprng::choice3_2048(g, rows);
  nprng::choice3_2048(g, cols);

  wtrans_kernel<<<768, 256, 0, stream>>>(Wq, Wk, Wv, WTc);

  proj_kernel<<<768, 256, 0, stream>>>(xq, xk, xv, WTc, bq, bk, bv, QP, KP, VPT);

  dim3 agrid(SEQ / 16, NBATCH);
  attn_kernel<<<agrid, 256, 0, stream>>>(
      QP, KP, VPT, out, (int)rows[0], (int)cols[0], (int)rows[1], (int)cols[1],
      (int)rows[2], (int)cols[2]);
}

// Round 7
// 158.393 us; speedup vs baseline: 2.4986x; 1.0648x over previous
//
#include <hip/hip_runtime.h>
#include <cstdint>
#include <cstddef>
#include <math.h>

#define SEQ    2048
#define NBATCH 4
#define DIN    1024
#define DH     64

typedef __attribute__((ext_vector_type(8))) short  short8;   // 8 x bf16 (4 VGPRs)
typedef __attribute__((ext_vector_type(4))) float  floatx4;  // MFMA C/D
typedef __attribute__((ext_vector_type(4))) unsigned short ushort4v;

#define MFMA16(a, b, c) __builtin_amdgcn_mfma_f32_16x16x32_bf16((a), (b), (c), 0, 0, 0)

__device__ __forceinline__ unsigned short f2bf(float x) {
  unsigned u = __float_as_uint(x);
  return (unsigned short)((u + 0x8000u) >> 16);   // round-half-up; values finite
}
__device__ __forceinline__ float bf2f(unsigned short h) {
  return __uint_as_float(((unsigned)h) << 16);
}

// async global->LDS DMA: no dest VGPR, scheduler cannot sink it.
// deposits at lds_base + lane*size.
__device__ __forceinline__ void async_cp4(const void* g, void* l) {
  __builtin_amdgcn_global_load_lds(
      (const __attribute__((address_space(1))) void*)g,
      (__attribute__((address_space(3))) void*)l, 4, 0, 0);
}
__device__ __forceinline__ void async_cp16(const void* g, void* l) {
  __builtin_amdgcn_global_load_lds(
      (const __attribute__((address_space(1))) void*)g,
      (__attribute__((address_space(3))) void*)l, 16, 0, 0);
}

// ======================= host-side numpy RNG replication =======================
namespace nprng {

struct PCG64 {
  __uint128_t state, inc;
  bool has_uint32;
  uint32_t uinteger;
};

static inline void pcg_step(PCG64 &g) {
  const __uint128_t MULT =
      (((__uint128_t)0x2360ed051fc65da4ULL) << 64) | 0x4385df649fccf645ULL;
  g.state = g.state * MULT + g.inc;
}

static inline uint64_t pcg_output(const PCG64 &g) {
  uint64_t hi = (uint64_t)(g.state >> 64);
  uint64_t lo = (uint64_t)g.state;
  uint64_t x = hi ^ lo;
  unsigned rot = (unsigned)(g.state >> 122) & 63u;
  return (x >> rot) | (x << ((64u - rot) & 63u));
}

static inline uint64_t pcg_next64(PCG64 &g) { pcg_step(g); return pcg_output(g); }

static inline uint32_t pcg_next32(PCG64 &g) {
  if (g.has_uint32) { g.has_uint32 = false; return g.uinteger; }
  uint64_t n = pcg_next64(g);
  g.has_uint32 = true;
  g.uinteger = (uint32_t)(n >> 32);
  return (uint32_t)(n & 0xffffffffu);
}

static inline void pcg_seed_from_seedseq0(PCG64 &g) {
  const uint32_t MULT_A = 0x931e8875u;
  const uint32_t MULT_B = 0x58f38dedu;
  const uint32_t MIX_L  = 0xca01f9ddu;
  const uint32_t MIX_R  = 0x4973f715u;
  uint32_t hc = 0x43b0d7e5u;  // INIT_A
  uint32_t pool[4];
  for (int i = 0; i < 4; i++) {
    uint32_t v = 0u;
    v ^= hc; hc *= MULT_A; v *= hc; v ^= v >> 16;
    pool[i] = v;
  }
  for (int is = 0; is < 4; is++) {
    for (int id = 0; id < 4; id++) {
      if (is == id) continue;
      uint32_t h = pool[is];
      h ^= hc; hc *= MULT_A; h *= hc; h ^= h >> 16;
      uint32_t r = (pool[id] * MIX_L) ^ (h * MIX_R);
      r ^= r >> 16;
      pool[id] = r;
    }
  }
  uint32_t hb = 0x8b51f9ddu;  // INIT_B
  uint32_t w[8];
  for (int i = 0; i < 8; i++) {
    uint32_t v = pool[i & 3];
    v ^= hb; hb *= MULT_B; v *= hb; v ^= v >> 16;
    w[i] = v;
  }
  uint64_t sv[4];
  for (int k = 0; k < 4; k++)
    sv[k] = (uint64_t)w[2 * k] | ((uint64_t)w[2 * k + 1] << 32);
  __uint128_t initstate = (((__uint128_t)sv[0]) << 64) | sv[1];
  __uint128_t initseq   = (((__uint128_t)sv[2]) << 64) | sv[3];
  g.state = 0; g.inc = (initseq << 1) | 1;
  pcg_step(g);
  g.state += initstate;
  pcg_step(g);
  g.has_uint32 = false; g.uinteger = 0;
}

static inline uint32_t bounded32(PCG64 &g, uint32_t rng /*inclusive max*/) {
  if (rng == 0) return 0;
  const uint32_t rng_excl = rng + 1u;
  uint64_t m = (uint64_t)pcg_next32(g) * (uint64_t)rng_excl;
  uint32_t leftover = (uint32_t)m;
  if (leftover < rng_excl) {
    const uint32_t threshold = (uint32_t)(0xffffffffu - rng) % rng_excl;
    while (leftover < threshold) {
      m = (uint64_t)pcg_next32(g) * (uint64_t)rng_excl;
      leftover = (uint32_t)m;
    }
  }
  return (uint32_t)(m >> 32);
}

static inline void choice3_2048(PCG64 &g, long long idx[3]) {
  const int pop = 2048, sz = 3;
  uint64_t hs[4] = { (uint64_t)-1, (uint64_t)-1, (uint64_t)-1, (uint64_t)-1 };
  const uint64_t mask = 3;
  for (int j = pop - sz; j < pop; j++) {
    uint64_t val = (uint64_t)bounded32(g, (uint32_t)j);
    uint64_t loc = val & mask;
    while (hs[loc] != (uint64_t)-1 && hs[loc] != val) loc = (loc + 1) & mask;
    if (hs[loc] == (uint64_t)-1) {
      hs[loc] = val;
      idx[j - pop + sz] = (long long)val;
    } else {
      loc = (uint64_t)j & mask;
      while (hs[loc] != (uint64_t)-1) loc = (loc + 1) & mask;
      hs[loc] = (uint64_t)j;
      idx[j - pop + sz] = (long long)j;
    }
  }
  for (int i = 2; i >= 1; i--) {
    uint32_t j = bounded32(g, (uint32_t)i);
    long long t = idx[j]; idx[j] = idx[i]; idx[i] = t;
  }
}

}  // namespace nprng

// ==================== kernel 0: W -> chunked W^T bf16 (tiny) ==================
// WTc layout: [proj][kc=k/128][col(64)][kk=k%128] bf16 — each (proj,kc) chunk is
// a contiguous 16 KB block so proj can DMA it with size-16 global_load_lds.
__global__ __launch_bounds__(256) void wtrans_kernel(
    const float* __restrict__ Wq, const float* __restrict__ Wk,
    const float* __restrict__ Wv, unsigned short* __restrict__ WTc) {
  int idx = blockIdx.x * 256 + threadIdx.x;     // 0 .. 3*64*1024-1
  int p   = idx >> 16;
  int rem = idx & 65535;
  int n   = rem >> 10;
  int k   = rem & 1023;
  const float* W = (p == 0) ? Wq : (p == 1) ? Wk : Wv;
  unsigned short v = f2bf(W[k * 64 + n]);
  int dst = ((p * 8 + (k >> 7)) * 64 + n) * 128 + (k & 127);
  WTc[dst] = v;
}

// ======== projections: double-buffered global_load_lds bf16 MFMA GEMM =========
// grid 768 x 256 thr (4 waves). Block = 32 rows of the concatenated 24576-row
// [q;k;v] input; K=1024 in 8 chunks of 128, X/W staged via async DMA into
// ALTERNATING LDS buffers (chunk k+1 issued right after the barrier, computed
// chunk k hides part of its latency). Output written in MFMA-FRAGMENT-MAJOR
// layouts consumed by attn:
//   Qf: per (b, qt=16-row tile) 2048 B chunk: frag s(2) x lane(64) x 16 B,
//       frag s lane l -> Q[qt*16+(l&15)][s*32+(l>>4)*8 + j]
//   Kf: per (b, t=64-row tile) 8192 B: frag (c*2+s), lane l ->
//       K[t*64+16c+(l&15)][s*32+(l>>4)*8+j]
//   Vf: per (b, t) 8192 B: frag (s*4+c), lane l ->
//       V[t*64+s*32+(l>>4)*8+j][16c+(l&15)]
__global__ __launch_bounds__(256, 2) void proj_kernel(
    const float* __restrict__ xq, const float* __restrict__ xk,
    const float* __restrict__ xv, const unsigned short* __restrict__ WTc,
    const float* __restrict__ bq, const float* __restrict__ bk,
    const float* __restrict__ bv,
    unsigned short* __restrict__ Qf, unsigned short* __restrict__ Kf,
    unsigned short* __restrict__ Vf) {
  const int m0g  = blockIdx.x * 32;        // 0..24544
  const int proj = m0g >> 13;              // 0,1,2
  const int m0   = m0g & 8191;             // row within proj
  const float* X    = (proj == 0) ? xq : (proj == 1) ? xk : xv;
  const float* bias = (proj == 0) ? bq : (proj == 1) ? bk : bv;

  const int tid  = threadIdx.x;
  const int w    = tid >> 6;
  const int l    = tid & 63;
  const int quad = l >> 4;
  const int lx   = l & 15;
  const int mr   = (w & 1) * 16;           // wave's row half
  const int nc   = (w >> 1) * 32;          // wave's col half

  // LDS: X dbuf 2x16896 B (32 rows x 132 f32), W dbuf 2x16640 B (16 grp x 520
  // bf16). Cs epilogue staging aliases the X region (dead after the loop).
  __shared__ __align__(16) char LDSbuf[2 * 16896 + 2 * 16640];

  const float* Xblk = X + (size_t)m0 * DIN;
  const unsigned short* Wpj = WTc + (size_t)proj * 8 * 8192;

  floatx4 acc0 = {0.f, 0.f, 0.f, 0.f}, acc1 = acc0;

  // stage chunk kc into buffer buf (X rows 8w..8w+7, W groups 4w..4w+3 / wave)
  auto stage = [&](int kc, int buf) {
    float* Xs = (float*)(LDSbuf + buf * 16896);
    unsigned short* Ws = (unsigned short*)(LDSbuf + 2 * 16896 + buf * 16640);
#pragma unroll
    for (int i = 0; i < 8; i++) {
      const int r = 8 * w + i;
      const float* g = Xblk + (size_t)r * DIN + kc * 128;
      async_cp4(g + l,      &Xs[r * 132]);
      async_cp4(g + 64 + l, &Xs[r * 132 + 64]);
    }
#pragma unroll
    for (int i = 0; i < 4; i++) {
      const int g4 = 4 * w + i;
      const unsigned short* gsrc = Wpj + (size_t)kc * 8192 + g4 * 512;
      async_cp16((const char*)gsrc + l * 16, &Ws[g4 * 520]);
    }
  };

  stage(0, 0);
  for (int kc = 0; kc < 8; kc++) {
    __syncthreads();                       // drains DMA(kc); protects buffers
    if (kc < 7) stage(kc + 1, (kc + 1) & 1);
    const float* Xs = (const float*)(LDSbuf + (kc & 1) * 16896);
    const unsigned short* Ws =
        (const unsigned short*)(LDSbuf + 2 * 16896 + (kc & 1) * 16640);
#pragma unroll
    for (int ks = 0; ks < 4; ks++) {
      const float* ap = &Xs[(mr + lx) * 132 + ks * 32 + quad * 8];
      const float4 f0 = *(const float4*)ap;
      const float4 f1 = *(const float4*)(ap + 4);
      short8 a;
      a[0] = f2bf(f0.x); a[1] = f2bf(f0.y); a[2] = f2bf(f0.z); a[3] = f2bf(f0.w);
      a[4] = f2bf(f1.x); a[5] = f2bf(f1.y); a[6] = f2bf(f1.z); a[7] = f2bf(f1.w);
      const int c0 = nc + lx, c1 = nc + 16 + lx;
      const short8 b0 = *(const short8*)&Ws[(c0 >> 2) * 520 + (c0 & 3) * 128 + ks * 32 + quad * 8];
      const short8 b1 = *(const short8*)&Ws[(c1 >> 2) * 520 + (c1 & 3) * 128 + ks * 32 + quad * 8];
      acc0 = MFMA16(a, b0, acc0);
      acc1 = MFMA16(a, b1, acc1);
    }
  }
  __syncthreads();                         // all reads done; Cs may alias X

  float (*Cs)[68] = (float(*)[68])LDSbuf;  // 32 x 68 f32 = 8704 B
  const float bb0 = bias[nc + lx], bb1 = bias[nc + 16 + lx];
#pragma unroll
  for (int i = 0; i < 4; i++) {
    Cs[mr + quad * 4 + i][nc + lx]      = acc0[i] + bb0;
    Cs[mr + quad * 4 + i][nc + 16 + lx] = acc1[i] + bb1;
  }
  __syncthreads();

  const int bq_ = m0 >> 11;                // batch
  const int s0  = m0 & 2047;               // seq offset within batch
  if (proj == 0) {
    // Q: two 16-row tiles, frag s, lane ll
    const int ti = tid >> 7, s = (tid >> 6) & 1, ll = tid & 63;
    const int lxx = ll & 15, qq = ll >> 4;
    short8 v;
#pragma unroll
    for (int j = 0; j < 8; j++) v[j] = (short)f2bf(Cs[ti * 16 + lxx][s * 32 + qq * 8 + j]);
    char* dst = (char*)Qf + ((size_t)(bq_ * 128 + (s0 >> 4) + ti)) * 2048 + s * 1024 + ll * 16;
    *(short8*)dst = v;
  } else if (proj == 1) {
    // K: half of a 64-row tile -> frags (c0+ci, s)
    const int ci = tid >> 7, s = (tid >> 6) & 1, ll = tid & 63;
    const int lxx = ll & 15, qq = ll >> 4;
    const int c = ((s0 >> 4) & 3) + ci;
    short8 v;
#pragma unroll
    for (int j = 0; j < 8; j++) v[j] = (short)f2bf(Cs[ci * 16 + lxx][s * 32 + qq * 8 + j]);
    char* dst = (char*)Kf + ((size_t)(bq_ * 32 + (s0 >> 6))) * 8192 + (c * 2 + s) * 1024 + ll * 16;
    *(short8*)dst = v;
  } else {
    // V: s-half of a 64-row tile -> frags (sh, c=0..3); lane gathers 8 seq rows
    const int c = tid >> 6, ll = tid & 63;
    const int lxx = ll & 15, qq = ll >> 4;
    const int sh = (s0 >> 5) & 1;
    short8 v;
#pragma unroll
    for (int j = 0; j < 8; j++) v[j] = (short)f2bf(Cs[qq * 8 + j][c * 16 + lxx]);
    char* dst = (char*)Vf + ((size_t)(bq_ * 32 + (s0 >> 6))) * 8192 + (sh * 4 + c) * 1024 + ll * 16;
    *(short8*)dst = v;
  }
}

// ============ flash attention: fragment-major direct loads, 1 barrier =========
// grid (128, 4), 256 threads (4 waves). Block = 16 q-rows; wave w processes
// key-tiles t = w, w+4, ... with independent online-softmax state; merged once.
// All Q/K/V fragment loads are per-wave LINEAR global reads (chunk + lane*16):
// perfect coalescing, no LDS staging, no barriers, no bank conflicts.
__global__ __launch_bounds__(256, 2) void attn_kernel(
    const unsigned short* __restrict__ Qf, const unsigned short* __restrict__ Kf,
    const unsigned short* __restrict__ Vf, float* __restrict__ out,
    int R0, int C0, int R1, int C1, int R2, int C2) {
  const int b    = blockIdx.y;
  const int bx   = blockIdx.x;
  const int qi   = (bx & 1) ? (127 - (bx >> 1)) : (bx >> 1);  // heavy/light pairing
  const int q0   = qi * 16;
  const int tid  = threadIdx.x;
  const int w    = tid >> 6;
  const int l    = tid & 63;
  const int quad = l >> 4;
  const int lx   = l & 15;

  __shared__ unsigned short Ps[4][16][72];
  __shared__ float Os[4][16][64];
  __shared__ float mS[4][16], lS[4][16];
  __shared__ float lgS[3];
  __shared__ int   lgF[3];

  const char* Qc = (const char*)Qf + ((size_t)(b * 128 + qi)) * 2048 + l * 16;
  const short8 aq0 = *(const short8*)Qc;
  const short8 aq1 = *(const short8*)(Qc + 1024);

  floatx4 O[4];
  float m_i[4], l_i[4];
#pragma unroll
  for (int c = 0; c < 4; c++) O[c] = (floatx4){0.f, 0.f, 0.f, 0.f};
#pragma unroll
  for (int i = 0; i < 4; i++) { m_i[i] = -INFINITY; l_i[i] = 0.f; }

  const int T = (q0 + 79) >> 6;   // key-tiles needed (64 keys each)

  for (int t = w; t < T; t += 4) {
    const int k0 = t << 6;
    const bool mT = (t == T - 1);

    const char* Kc = (const char*)Kf + ((size_t)(b * 32 + t)) * 8192 + l * 16;
    const char* Vc = (const char*)Vf + ((size_t)(b * 32 + t)) * 8192 + l * 16;
    short8 kf[8], vf[8];
#pragma unroll
    for (int f = 0; f < 8; f++) {
      kf[f] = *(const short8*)(Kc + f * 1024);
      vf[f] = *(const short8*)(Vc + f * 1024);
    }

    floatx4 sc[4];
#pragma unroll
    for (int c = 0; c < 4; c++) {
      sc[c] = (floatx4){0.f, 0.f, 0.f, 0.f};
      sc[c] = MFMA16(aq0, kf[2 * c], sc[c]);
      sc[c] = MFMA16(aq1, kf[2 * c + 1], sc[c]);
    }

    float mt[4], al[4];
#pragma unroll
    for (int i = 0; i < 4; i++) {
      const int rowg = q0 + quad * 4 + i;
      float vmax = -INFINITY;
#pragma unroll
      for (int c = 0; c < 4; c++) {
        float v = sc[c][i] * 0.125f;
        if (mT && (k0 + 16 * c + lx) > rowg) v = -INFINITY;
        sc[c][i] = v;
        vmax = fmaxf(vmax, v);
      }
      mt[i] = vmax;
    }
#pragma unroll
    for (int i = 0; i < 4; i++) {
#pragma unroll
      for (int off = 8; off >= 1; off >>= 1)
        mt[i] = fmaxf(mt[i], __shfl_xor(mt[i], off));
      const float mn = fmaxf(m_i[i], mt[i]);
      al[i] = __expf(m_i[i] - mn);
      m_i[i] = mn;
      float s = 0.f;
#pragma unroll
      for (int c = 0; c < 4; c++) {
        float p = __expf(sc[c][i] - mn);
        Ps[w][quad * 4 + i][16 * c + lx] = f2bf(p);
        s += p;
      }
#pragma unroll
      for (int off = 8; off >= 1; off >>= 1) s += __shfl_xor(s, off);
      l_i[i] = l_i[i] * al[i] + s;
    }
#pragma unroll
    for (int c = 0; c < 4; c++)
#pragma unroll
      for (int i = 0; i < 4; i++) O[c][i] *= al[i];
    asm volatile("" ::: "memory");  // keep ds_reads below the ds_writes above
    const short8 pf0 = *(const short8*)&Ps[w][lx][quad * 8];
    const short8 pf1 = *(const short8*)&Ps[w][lx][32 + quad * 8];
#pragma unroll
    for (int c = 0; c < 4; c++) {
      O[c] = MFMA16(pf0, vf[c],     O[c]);
      O[c] = MFMA16(pf1, vf[4 + c], O[c]);
    }
  }

  // deposit per-wave state
  if (lx == 0) {
#pragma unroll
    for (int i = 0; i < 4; i++) {
      mS[w][quad * 4 + i] = m_i[i];
      lS[w][quad * 4 + i] = l_i[i];
    }
  }
#pragma unroll
  for (int c = 0; c < 4; c++)
#pragma unroll
    for (int i = 0; i < 4; i++) Os[w][quad * 4 + i][16 * c + lx] = O[c][i];

  // wave 0: logits for global pairs above the diagonal (lane l owns dim d=l)
  if (w == 0) {
#pragma unroll
    for (int p = 0; p < 3; p++) {
      const int R = (p == 0) ? R0 : (p == 1) ? R1 : R2;
      const int C = (p == 0) ? C0 : (p == 1) ? C1 : C2;
      const int act = (R >= q0 && R < q0 + 16 && C > R);
      float d = 0.f;
      if (act) {
        const int dd = l;
        const char* qa = (const char*)Qf + ((size_t)(b * 128 + (R >> 4))) * 2048 +
                         (dd >> 5) * 1024 + ((R & 15) + ((dd >> 3) & 3) * 16) * 16 + (dd & 7) * 2;
        const char* ka = (const char*)Kf + ((size_t)(b * 32 + (C >> 6))) * 8192 +
                         (((C >> 4) & 3) * 2 + (dd >> 5)) * 1024 +
                         ((C & 15) + ((dd >> 3) & 3) * 16) * 16 + (dd & 7) * 2;
        d = bf2f(*(const unsigned short*)qa) * bf2f(*(const unsigned short*)ka);
#pragma unroll
        for (int off = 32; off >= 1; off >>= 1) d += __shfl_xor(d, off);
        d *= 0.125f;
      }
      if (l == 0) { lgF[p] = act; lgS[p] = d; }
    }
  }
  __syncthreads();

  // merge the 4 wave states (+ pair fixups), normalize, store
  {
    const int row = tid >> 4;          // 0..15
    const int d0  = (tid & 15) * 4;    // 0..60
    const int Rs[3] = {R0, R1, R2};
    const int Cs3[3] = {C0, C1, C2};

    float mf = -INFINITY;
#pragma unroll
    for (int w4 = 0; w4 < 4; w4++) mf = fmaxf(mf, mS[w4][row]);
#pragma unroll
    for (int p = 0; p < 3; p++)
      if (lgF[p] && (Rs[p] - q0) == row) mf = fmaxf(mf, lgS[p]);

    float lf = 0.f;
    float o0 = 0.f, o1 = 0.f, o2 = 0.f, o3 = 0.f;
#pragma unroll
    for (int w4 = 0; w4 < 4; w4++) {
      const float a = __expf(mS[w4][row] - mf);
      lf += a * lS[w4][row];
      const float* op = &Os[w4][row][d0];
      o0 += a * op[0]; o1 += a * op[1]; o2 += a * op[2]; o3 += a * op[3];
    }
#pragma unroll
    for (int p = 0; p < 3; p++) {
      if (lgF[p] && (Rs[p] - q0) == row) {
        const float pe = __expf(lgS[p] - mf);
        lf += pe;
        const int C = Cs3[p];
        float vv[4];
#pragma unroll
        for (int j = 0; j < 4; j++) {
          const int dim = d0 + j;
          const char* va = (const char*)Vf + ((size_t)(b * 32 + (C >> 6))) * 8192 +
                           (((C >> 5) & 1) * 4 + (dim >> 4)) * 1024 +
                           ((dim & 15) + ((C >> 3) & 3) * 16) * 16 + (C & 7) * 2;
          vv[j] = bf2f(*(const unsigned short*)va);
        }
        o0 += pe * vv[0]; o1 += pe * vv[1]; o2 += pe * vv[2]; o3 += pe * vv[3];
      }
    }
    const float inv = 1.0f / lf;
    float4 r;
    r.x = o0 * inv; r.y = o1 * inv; r.z = o2 * inv; r.w = o3 * inv;
    *(float4*)(out + ((size_t)b * SEQ + q0 + row) * 64 + d0) = r;
  }
}

// ================================= launch =====================================
extern "C" void kernel_launch(void* const* d_in, const int* in_sizes, int n_in,
                              void* d_out, int out_size, void* d_ws,
                              size_t ws_size, hipStream_t stream) {
  const float* xq = (const float*)d_in[0];
  const float* xk = (const float*)d_in[1];
  const float* xv = (const float*)d_in[2];
  const float* Wq = (const float*)d_in[3];
  const float* bq = (const float*)d_in[4];
  const float* Wk = (const float*)d_in[5];
  const float* bk = (const float*)d_in[6];
  const float* Wv = (const float*)d_in[7];
  const float* bv = (const float*)d_in[8];
  float* out = (float*)d_out;

  // workspace (bf16): Qf 1MB, Kf 1MB, Vf 1MB, WTc 384KB (fragment-major layouts)
  unsigned short* Qf  = (unsigned short*)d_ws;
  unsigned short* Kf  = Qf + (size_t)NBATCH * SEQ * 64;
  unsigned short* Vf  = Kf + (size_t)NBATCH * SEQ * 64;
  unsigned short* WTc = Vf + (size_t)NBATCH * SEQ * 64;

  nprng::PCG64 g;
  nprng::pcg_seed_from_seedseq0(g);
  long long rows[3], cols[3];
  nprng::choice3_2048(g, rows);
  nprng::choice3_2048(g, cols);

  wtrans_kernel<<<768, 256, 0, stream>>>(Wq, Wk, Wv, WTc);

  proj_kernel<<<768, 256, 0, stream>>>(xq, xk, xv, WTc, bq, bk, bv, Qf, Kf, Vf);

  dim3 agrid(SEQ / 16, NBATCH);
  attn_kernel<<<agrid, 256, 0, stream>>>(
      Qf, Kf, Vf, out, (int)rows[0], (int)cols[0], (int)rows[1], (int)cols[1],
      (int)rows[2], (int)cols[2]);
}